// Round 2
// baseline (28111.581 us; speedup 1.0000x reference)
//
#include <hip/hip_runtime.h>
#include <hip/hip_bf16.h>
#include <hip/hip_cooperative_groups.h>

namespace cg = cooperative_groups;

#define B_   256
#define L_   336
#define NIN  8
#define H_   512
#define PL_  96
#define KC   64
#define BT   32
#define GT   128

typedef unsigned short u16;
typedef __attribute__((ext_vector_type(8))) short short8;
typedef __attribute__((ext_vector_type(4))) float f32x4;

__device__ __forceinline__ float sigm(float x)   { return 1.0f / (1.0f + __expf(-x)); }
__device__ __forceinline__ float tanhf_(float x) { return 1.0f - 2.0f / (1.0f + __expf(2.0f * x)); }
__device__ __forceinline__ u16 f2b(float f) {
    __hip_bfloat16 h = __float2bfloat16(f);
    return __builtin_bit_cast(u16, h);
}
__device__ __forceinline__ float b2f(u16 u) {
    union { unsigned int i; float f; } v; v.i = ((unsigned int)u) << 16; return v.f;
}

// ============================ fused persistent path ============================

// A-panel: 32 batch rows x up-to-512 K elems, +8 pad => row stride 1040 B
// (1040 B = 260 dwords == 4 mod 32 -> same bank-residue class as the verified
// baseline's 144 B stride; 2-way aliasing on wave64 is free per m136)
struct EncSM {
    u16   in_s[32][520];
    float g_s[128][33];
};
struct AttnSM {
    float hs[H_];
    float red[256];
    u16   Es[48 * H_];
    float scores[48];
};
union SMU { EncSM enc; AttnSM attn; };

// ---- register-weight MFMA over one staged segment (K = NK*32) ----
#define MFMA_SEG(NK, WB, KOFS)                                                              \
    _Pragma("unroll")                                                                       \
    for (int kc = 0; kc < (NK); ++kc) {                                                     \
        const int kk = (kc << 5) + klo;                                                     \
        short8 a0 = *(const short8*)&sm.enc.in_s[lane & 15][kk];                            \
        short8 a1 = *(const short8*)&sm.enc.in_s[16 + (lane & 15)][kk];                     \
        acc[0][0] = __builtin_amdgcn_mfma_f32_16x16x32_bf16(a0, WB[0][(KOFS) + kc], acc[0][0], 0, 0, 0); \
        acc[1][0] = __builtin_amdgcn_mfma_f32_16x16x32_bf16(a1, WB[0][(KOFS) + kc], acc[1][0], 0, 0, 0); \
        acc[0][1] = __builtin_amdgcn_mfma_f32_16x16x32_bf16(a0, WB[1][(KOFS) + kc], acc[0][1], 0, 0, 0); \
        acc[1][1] = __builtin_amdgcn_mfma_f32_16x16x32_bf16(a1, WB[1][(KOFS) + kc], acc[1][1], 0, 0, 0); \
    }

// C/D layout (m89-verified): col(n)=lane&15, row(m)=(lane>>4)*4+reg
#define WRITE_GS()                                                                          \
    _Pragma("unroll")                                                                       \
    for (int mt = 0; mt < 2; ++mt)                                                          \
    _Pragma("unroll")                                                                       \
    for (int nt = 0; nt < 2; ++nt) {                                                        \
        const int gi = (((wv << 1) + nt) << 4) + (lane & 15);                               \
        const int brow = (mt << 4) + ((lane >> 4) << 2);                                    \
        _Pragma("unroll")                                                                   \
        for (int r = 0; r < 4; ++r) sm.enc.g_s[gi][brow + r] = acc[mt][nt][r];              \
    }

// load a 16-chunk (K=512) weight slice into registers, fragment layout
// (W row = wv*512 + j0 + nt*16 + (lane&15) — identical mapping to the
//  verified baseline's w_s[gi] indexing)
#define LOAD_W16_OFS(WB, OFS, PTR)                                                          \
    _Pragma("unroll")                                                                       \
    for (int nt = 0; nt < 2; ++nt) {                                                        \
        const size_t row_ = (size_t)((wv << 9) + j0 + (nt << 4) + (lane & 15));             \
        _Pragma("unroll")                                                                   \
        for (int kc = 0; kc < 16; ++kc)                                                     \
            WB[nt][(OFS) + kc] = *(const short8*)((PTR) + (row_ << 9) + (kc << 5) + klo);   \
    }

__device__ __forceinline__ void stage_h(EncSM& e, const u16* __restrict__ src,
                                        int batch0, int tid) {
    #pragma unroll
    for (int i = 0; i < 8; ++i) {
        const int idx = tid + (i << 8);
        const int row = idx >> 6, kq = idx & 63;
        *(uint4*)&e.in_s[row][kq << 3] =
            *(const uint4*)(src + ((size_t)(batch0 + row) << 9) + (kq << 3));
    }
}

__device__ __forceinline__ void cell_phase(EncSM& e,
    const float* __restrict__ bias, const float* __restrict__ w0col,
    const float* __restrict__ yprev, float* __restrict__ cbuf,
    u16* __restrict__ hbf_out, float* __restrict__ hf_out,
    u16* __restrict__ Ebuf, int te, int batch0, int j0, int tid)
{
    #pragma unroll
    for (int eix = 0; eix < 4; ++eix) {
        const int idx = tid + (eix << 8);
        const int b = idx >> 5, j = idx & 31;
        const int bg = batch0 + b, jg = j0 + j;
        float pre[4];
        #pragma unroll
        for (int q = 0; q < 4; ++q) {
            const int r = (q << 9) + jg;
            float v = e.g_s[(q << 5) + j][b] + bias[r];
            if (w0col) v += yprev[bg] * w0col[r];
            pre[q] = v;
        }
        const float iv = sigm(pre[0]);
        const float fv = sigm(pre[1]);
        const float gv = tanhf_(pre[2]);
        const float ov = sigm(pre[3]);
        const size_t ci = ((size_t)bg << 9) + jg;
        const float cold = cbuf[ci];
        const float cn = fv * cold + iv * gv;
        const float hn = ov * tanhf_(cn);
        cbuf[ci] = cn;
        hbf_out[ci] = f2b(hn);
        if (hf_out) hf_out[ci] = hn;
        if (Ebuf) Ebuf[((size_t)bg * L_ + te) * H_ + jg] = f2b(hn);
    }
}

// one recurrent step over two K=512 segments with register weights;
// segment-1 global loads issued before segment-0 MFMAs (T14 split).
__device__ __forceinline__ void step2seg(SMU& sm, const short8 (&wB)[2][32],
    const u16* __restrict__ src0, const u16* __restrict__ src1,
    const float* __restrict__ bias, const float* __restrict__ w0col,
    const float* __restrict__ yprev, float* __restrict__ cbuf,
    u16* __restrict__ hbf, float* __restrict__ hf, u16* __restrict__ Ebuf, int te,
    int batch0, int j0, int tid, int wv, int lane, int klo)
{
    __syncthreads();
    stage_h(sm.enc, src0, batch0, tid);
    uint4 pre2[8];
    #pragma unroll
    for (int i = 0; i < 8; ++i) {
        const int idx = tid + (i << 8);
        pre2[i] = *(const uint4*)(src1 + ((size_t)(batch0 + (idx >> 6)) << 9) + ((idx & 63) << 3));
    }
    __syncthreads();
    f32x4 acc[2][2] = {};
    MFMA_SEG(16, wB, 0);
    __syncthreads();
    #pragma unroll
    for (int i = 0; i < 8; ++i) {
        const int idx = tid + (i << 8);
        *(uint4*)&sm.enc.in_s[idx >> 6][(idx & 63) << 3] = pre2[i];
    }
    __syncthreads();
    MFMA_SEG(16, wB, 16);
    WRITE_GS();
    __syncthreads();
    cell_phase(sm.enc, bias, w0col, yprev, cbuf, hbf, hf, Ebuf, te, batch0, j0, tid);
}

// y_{step-1} = h.Wfc + b, then flash-style attention over E with one-tile
// register prefetch. step==PL_: y only.
__device__ __forceinline__ void attn_phase(SMU& sm,
    const float* __restrict__ hf, const u16* __restrict__ E,
    const float* __restrict__ Wfc, const float* __restrict__ bfc,
    u16* __restrict__ ctxb, float* __restrict__ yprev,
    float* __restrict__ out, int step, int b, int tid)
{
    AttnSM& a = sm.attn;
    const int wv = tid >> 6, lane = tid & 63;
    __syncthreads();
    a.hs[tid]       = hf[((size_t)b << 9) + tid];
    a.hs[tid + 256] = hf[((size_t)b << 9) + tid + 256];
    __syncthreads();
    float p = a.hs[tid] * Wfc[tid] + a.hs[tid + 256] * Wfc[tid + 256];
    a.red[tid] = p;
    __syncthreads();
    for (int s = 128; s > 0; s >>= 1) {
        if (tid < s) a.red[tid] += a.red[tid + s];
        __syncthreads();
    }
    if (tid == 0) {
        if (step > 0) {
            float y = a.red[0] + bfc[0];
            yprev[b] = y;
            out[b * PL_ + (step - 1)] = y;
        } else {
            yprev[b] = 0.0f;   // reference: y0 = zeros
        }
    }
    if (step == PL_) return;   // final: y only

    float m = -1e30f, d = 0.0f, c0a = 0.0f, c1a = 0.0f;
    const int k0 = tid, k1 = tid + 256;
    const uint4* Ebase = (const uint4*)(E + (((size_t)b * L_) << 9));
    uint4 pre[12];
    #pragma unroll
    for (int i = 0; i < 12; ++i) pre[i] = Ebase[tid + (i << 8)];

    for (int l0 = 0; l0 < L_; l0 += 48) {
        __syncthreads();
        {
            uint4* dst = (uint4*)a.Es;
            #pragma unroll
            for (int i = 0; i < 12; ++i) dst[tid + (i << 8)] = pre[i];
        }
        __syncthreads();
        if (l0 + 48 < L_) {
            const uint4* nx = Ebase + ((size_t)(l0 + 48) << 6);
            #pragma unroll
            for (int i = 0; i < 12; ++i) pre[i] = nx[tid + (i << 8)];
        }
        #pragma unroll
        for (int s = 0; s < 12; ++s) {
            const int l = wv * 12 + s;
            const u16* er = &a.Es[(l << 9) + (lane << 3)];
            float acc = 0.f;
            #pragma unroll
            for (int j = 0; j < 8; ++j)
                acc += a.hs[(lane << 3) + j] * b2f(er[j]);
            #pragma unroll
            for (int off = 32; off > 0; off >>= 1)
                acc += __shfl_xor(acc, off);
            if (lane == 0) a.scores[l] = acc;
        }
        __syncthreads();
        float mc = m;
        #pragma unroll
        for (int l = 0; l < 48; ++l) mc = fmaxf(mc, a.scores[l]);
        const float alpha = __expf(m - mc);
        d *= alpha; c0a *= alpha; c1a *= alpha;
        for (int l = 0; l < 48; ++l) {
            const float pl = __expf(a.scores[l] - mc);
            d += pl;
            c0a += pl * b2f(a.Es[(l << 9) + k0]);
            c1a += pl * b2f(a.Es[(l << 9) + k1]);
        }
        m = mc;
    }
    const float inv = 1.0f / d;
    ctxb[((size_t)b << 9) + k0] = f2b(c0a * inv);
    ctxb[((size_t)b << 9) + k1] = f2b(c1a * inv);
}

// Persistent kernel: whole encoder recurrence + decoder loop.
// blocks 0..127: L0 (then decoder cell); blocks 128..255: L1. Recurrent
// weights live in VGPRs for the whole kernel (loaded once per role).
__global__ __launch_bounds__(256, 1) void fused_kernel(
    const u16* __restrict__ xpad,
    const u16* __restrict__ Wih0p, const u16* __restrict__ Whh0b, const float* __restrict__ bias0,
    const u16* __restrict__ Wih1b, const u16* __restrict__ Whh1b, const float* __restrict__ bias1,
    u16* __restrict__ h0a, u16* __restrict__ h0b, float* __restrict__ c0,
    u16* __restrict__ h1a, u16* __restrict__ h1b,
    float* __restrict__ h1fa, float* __restrict__ h1fb, float* __restrict__ c1,
    u16* __restrict__ E,
    const u16* __restrict__ Wdihb, const u16* __restrict__ Wdhhb,
    const float* __restrict__ biasd, const float* __restrict__ w0col,
    u16* __restrict__ ctxb, float* __restrict__ ypv,
    const float* __restrict__ Wfc, const float* __restrict__ bfc,
    float* __restrict__ out)
{
    cg::grid_group grid = cg::this_grid();
    __shared__ SMU sm;
    const int tid = threadIdx.x;
    const int bid = blockIdx.x;
    const int wv = tid >> 6, lane = tid & 63;
    const int klo = (lane >> 4) << 3;

    if (bid < 128) {
        const int batch0 = (bid & 7) << 5;
        const int j0 = (bid >> 3) << 5;
        {   // ---------------- encoder layer 0 ----------------
            short8 wB[2][18];           // K=64 (x) + K=512 (h) fragments
            #pragma unroll
            for (int nt = 0; nt < 2; ++nt) {
                const size_t row_ = (size_t)((wv << 9) + j0 + (nt << 4) + (lane & 15));
                wB[nt][0] = *(const short8*)(Wih0p + (row_ << 6) + klo);
                wB[nt][1] = *(const short8*)(Wih0p + (row_ << 6) + 32 + klo);
            }
            LOAD_W16_OFS(wB, 2, Whh0b);
            for (int tau = 0; tau <= L_; ++tau) {
                if (tau < L_) {
                    __syncthreads();
                    {   // stage x_t (32 x 64)
                        const int row = tid >> 3, kq = tid & 7;
                        *(uint4*)&sm.enc.in_s[row][kq << 3] =
                            *(const uint4*)(xpad + ((size_t)(batch0 + row) * L_ + tau) * KC + (kq << 3));
                    }
                    uint4 pre2[8];
                    {   // prefetch h0 prev while x-MFMA runs
                        const u16* src1 = (tau & 1) ? h0b : h0a;
                        #pragma unroll
                        for (int i = 0; i < 8; ++i) {
                            const int idx = tid + (i << 8);
                            pre2[i] = *(const uint4*)(src1 + ((size_t)(batch0 + (idx >> 6)) << 9) + ((idx & 63) << 3));
                        }
                    }
                    __syncthreads();
                    f32x4 acc[2][2] = {};
                    MFMA_SEG(2, wB, 0);
                    __syncthreads();
                    #pragma unroll
                    for (int i = 0; i < 8; ++i) {
                        const int idx = tid + (i << 8);
                        *(uint4*)&sm.enc.in_s[idx >> 6][(idx & 63) << 3] = pre2[i];
                    }
                    __syncthreads();
                    MFMA_SEG(16, wB, 2);
                    WRITE_GS();
                    __syncthreads();
                    cell_phase(sm.enc, bias0, nullptr, nullptr, c0,
                               (tau & 1) ? h0a : h0b, nullptr, nullptr, 0,
                               batch0, j0, tid);
                }
                grid.sync();
            }
        }
        {   // ---------------- decoder: attention + cell ----------------
            short8 wB[2][32];
            LOAD_W16_OFS(wB, 0, Wdihb);
            LOAD_W16_OFS(wB, 16, Wdhhb);
            for (int t = 0; t < PL_; ++t) {
                attn_phase(sm, (t & 1) ? h1fb : h1fa, E, Wfc, bfc, ctxb, ypv, out, t, bid, tid);
                grid.sync();
                step2seg(sm, wB, ctxb, (t & 1) ? h1b : h1a,
                         biasd, w0col, ypv, c1,
                         (t & 1) ? h1a : h1b, (t & 1) ? h1fa : h1fb, nullptr, 0,
                         batch0, j0, tid, wv, lane, klo);
                grid.sync();
            }
        }
        attn_phase(sm, h1fa, E, Wfc, bfc, ctxb, ypv, out, PL_, bid, tid);
    } else {
        const int id = bid - 128;
        const int batch0 = (id & 7) << 5;
        const int j0 = (id >> 3) << 5;
        {   // ---------------- encoder layer 1 (one step behind) ----------------
            short8 wB[2][32];
            LOAD_W16_OFS(wB, 0, Wih1b);
            LOAD_W16_OFS(wB, 16, Whh1b);
            for (int tau = 0; tau <= L_; ++tau) {
                if (tau >= 1) {
                    const int te = tau - 1;
                    step2seg(sm, wB,
                             (tau & 1) ? h0b : h0a,            // ys0[te]
                             (te & 1) ? h1b : h1a,             // h1 prev
                             bias1, nullptr, nullptr, c1,
                             (te & 1) ? h1a : h1b, (te & 1) ? h1fa : h1fb, E, te,
                             batch0, j0, tid, wv, lane, klo);
                }
                grid.sync();
            }
        }
        for (int t = 0; t < PL_; ++t) {
            attn_phase(sm, (t & 1) ? h1fb : h1fa, E, Wfc, bfc, ctxb, ypv, out, t, bid, tid);
            grid.sync();
            grid.sync();   // cell phase runs on blocks 0..127
        }
        attn_phase(sm, h1fa, E, Wfc, bfc, ctxb, ypv, out, PL_, bid, tid);
    }
}

// ===================== verified multi-launch fallback path =====================

struct Seg { const u16* src; int stride; const u16* W; int nch; int ldw; };

struct SMOld {
    u16   in_s[BT][KC + 8];
    u16   w_s[GT][KC + 8];
    float g_s[GT][BT + 1];
};

__device__ void gates_gemm_cell(const Seg* segs,
    const float* __restrict__ bias, const float* __restrict__ w0col,
    const float* __restrict__ yprev,
    float* __restrict__ cbuf, u16* __restrict__ hbf_out, float* __restrict__ hf_out,
    u16* __restrict__ Ebuf, int te, int batch0, int j0, SMOld& sm)
{
    const int tid = threadIdx.x;
    const int wv = tid >> 6, lane = tid & 63;
    f32x4 acc[2][2] = {};

    for (int s = 0; s < 2; ++s) {
        const Seg sg = segs[s];
        for (int c = 0; c < sg.nch; ++c) {
            const int k0 = c * KC;
            __syncthreads();
            {
                const int b = tid >> 3, kq = tid & 7;
                const uint4* p = (const uint4*)(sg.src + (size_t)(batch0 + b) * sg.stride + k0) + kq;
                *(uint4*)&sm.in_s[b][kq << 3] = *p;
            }
            #pragma unroll
            for (int i = 0; i < 4; ++i) {
                const int idx = tid + (i << 8);
                const int gi = idx >> 3, kq = idx & 7;
                const int row = ((gi >> 5) << 9) + j0 + (gi & 31);
                const uint4* p = (const uint4*)(sg.W + (size_t)row * sg.ldw + k0) + kq;
                *(uint4*)&sm.w_s[gi][kq << 3] = *p;
            }
            __syncthreads();
            #pragma unroll
            for (int ks = 0; ks < 2; ++ks) {
                const int kk = (ks << 5) + ((lane >> 4) << 3);
                short8 a0 = *(const short8*)&sm.in_s[lane & 15][kk];
                short8 a1 = *(const short8*)&sm.in_s[16 + (lane & 15)][kk];
                #pragma unroll
                for (int nt = 0; nt < 2; ++nt) {
                    const int gi = (((wv << 1) + nt) << 4) + (lane & 15);
                    short8 bb = *(const short8*)&sm.w_s[gi][kk];
                    acc[0][nt] = __builtin_amdgcn_mfma_f32_16x16x32_bf16(a0, bb, acc[0][nt], 0, 0, 0);
                    acc[1][nt] = __builtin_amdgcn_mfma_f32_16x16x32_bf16(a1, bb, acc[1][nt], 0, 0, 0);
                }
            }
        }
    }
    __syncthreads();
    #pragma unroll
    for (int mt = 0; mt < 2; ++mt)
        #pragma unroll
        for (int nt = 0; nt < 2; ++nt) {
            const int gi = (((wv << 1) + nt) << 4) + (lane & 15);
            const int brow = (mt << 4) + ((lane >> 4) << 2);
            #pragma unroll
            for (int r = 0; r < 4; ++r)
                sm.g_s[gi][brow + r] = acc[mt][nt][r];
        }
    __syncthreads();

    #pragma unroll
    for (int e = 0; e < 4; ++e) {
        const int idx = tid + (e << 8);
        const int b = idx >> 5, j = idx & 31;
        const int bg = batch0 + b, jg = j0 + j;
        float pre[4];
        #pragma unroll
        for (int q = 0; q < 4; ++q) {
            const int r = (q << 9) + jg;
            float v = sm.g_s[(q << 5) + j][b] + bias[r];
            if (w0col) v += yprev[bg] * w0col[r];
            pre[q] = v;
        }
        const float iv = sigm(pre[0]);
        const float fv = sigm(pre[1]);
        const float gv = tanhf_(pre[2]);
        const float ov = sigm(pre[3]);
        const size_t ci = ((size_t)bg << 9) + jg;
        const float cold = cbuf[ci];
        const float cn = fv * cold + iv * gv;
        const float hn = ov * tanhf_(cn);
        cbuf[ci] = cn;
        hbf_out[ci] = f2b(hn);
        if (hf_out) hf_out[ci] = hn;
        if (Ebuf) Ebuf[((size_t)bg * L_ + te) * H_ + jg] = f2b(hn);
    }
}

__global__ __launch_bounds__(256) void enc_step_kernel(
    const u16* __restrict__ xpad, const u16* __restrict__ Wih0p, const u16* __restrict__ Whh0b,
    const float* __restrict__ bias0,
    const u16* __restrict__ Wih1b, const u16* __restrict__ Whh1b, const float* __restrict__ bias1,
    u16* h0a, u16* h0b, float* c0,
    u16* h1a, u16* h1b, float* h1fa, float* h1fb, float* c1,
    u16* E, int tau)
{
    __shared__ SMOld sm;
    const int bid = blockIdx.x;
    if (bid < 128) {
        if (tau >= L_) return;
        const int tb = bid & 7, th = bid >> 3;
        Seg segs[2];
        segs[0] = { xpad + tau * KC, L_ * KC, Wih0p, 1, KC };
        segs[1] = { (tau & 1) ? h0b : h0a, H_, Whh0b, 8, H_ };
        gates_gemm_cell(segs, bias0, nullptr, nullptr, c0,
                        (tau & 1) ? h0a : h0b, nullptr, nullptr, 0,
                        tb * BT, th * 32, sm);
    } else {
        if (tau == 0) return;
        const int te = tau - 1;
        const int id = bid - 128;
        const int tb = id & 7, th = id >> 3;
        Seg segs[2];
        segs[0] = { (tau & 1) ? h0b : h0a, H_, Wih1b, 8, H_ };
        segs[1] = { (te & 1) ? h1b : h1a, H_, Whh1b, 8, H_ };
        gates_gemm_cell(segs, bias1, nullptr, nullptr, c1,
                        (te & 1) ? h1a : h1b, (te & 1) ? h1fa : h1fb, E, te,
                        tb * BT, th * 32, sm);
    }
}

__global__ __launch_bounds__(256) void dec_step_kernel(
    const u16* __restrict__ ctxb, const float* __restrict__ yprev,
    const u16* __restrict__ Wdihb, const u16* __restrict__ Wdhhb,
    const float* __restrict__ biasd, const float* __restrict__ w0col,
    u16* h1a, u16* h1b, float* h1fa, float* h1fb, float* c1, int t)
{
    __shared__ SMOld sm;
    const int bid = blockIdx.x;
    const int tb = bid & 7, th = bid >> 3;
    Seg segs[2];
    segs[0] = { ctxb, H_, Wdihb, 8, H_ };
    segs[1] = { (t & 1) ? h1b : h1a, H_, Wdhhb, 8, H_ };
    gates_gemm_cell(segs, biasd, w0col, yprev, c1,
                    (t & 1) ? h1a : h1b, (t & 1) ? h1fa : h1fb, nullptr, 0,
                    tb * BT, th * 32, sm);
}

__global__ __launch_bounds__(256) void attn_step_kernel(
    const float* __restrict__ hf, const u16* __restrict__ E,
    const float* __restrict__ Wfc, const float* __restrict__ bfc,
    u16* __restrict__ ctxb, float* __restrict__ yprev,
    float* __restrict__ out, int step)
{
    __shared__ float hs[H_];
    __shared__ float red[256];
    __shared__ u16 Es[48 * H_];
    __shared__ float scores[48];
    const int tid = threadIdx.x;
    const int b = blockIdx.x;

    hs[tid]       = hf[((size_t)b << 9) + tid];
    hs[tid + 256] = hf[((size_t)b << 9) + tid + 256];
    __syncthreads();

    float p = hs[tid] * Wfc[tid] + hs[tid + 256] * Wfc[tid + 256];
    red[tid] = p;
    __syncthreads();
    for (int s = 128; s > 0; s >>= 1) {
        if (tid < s) red[tid] += red[tid + s];
        __syncthreads();
    }
    if (tid == 0) {
        if (step > 0) {
            float y = red[0] + bfc[0];
            yprev[b] = y;
            out[b * PL_ + (step - 1)] = y;
        } else {
            yprev[b] = 0.0f;
        }
    }
    if (step == PL_) return;

    const int wv = tid >> 6, lane = tid & 63;
    float m = -1e30f, d = 0.0f, c0a = 0.0f, c1a = 0.0f;
    const int k0 = tid, k1 = tid + 256;

    for (int l0 = 0; l0 < L_; l0 += 48) {
        __syncthreads();
        {
            const uint4* src = (const uint4*)(E + (((size_t)b * L_ + l0) << 9));
            uint4* dst = (uint4*)Es;
            #pragma unroll
            for (int i = 0; i < 12; ++i)
                dst[tid + (i << 8)] = src[tid + (i << 8)];
        }
        __syncthreads();
        #pragma unroll
        for (int s = 0; s < 12; ++s) {
            const int l = wv * 12 + s;
            const u16* er = &Es[(l << 9) + (lane << 3)];
            float acc = 0.f;
            #pragma unroll
            for (int j = 0; j < 8; ++j)
                acc += hs[(lane << 3) + j] * b2f(er[j]);
            #pragma unroll
            for (int off = 32; off > 0; off >>= 1)
                acc += __shfl_xor(acc, off);
            if (lane == 0) scores[l] = acc;
        }
        __syncthreads();
        float mc = m;
        #pragma unroll
        for (int l = 0; l < 48; ++l) mc = fmaxf(mc, scores[l]);
        const float alpha = __expf(m - mc);
        d *= alpha; c0a *= alpha; c1a *= alpha;
        for (int l = 0; l < 48; ++l) {
            const float pl = __expf(scores[l] - mc);
            d += pl;
            c0a += pl * b2f(Es[(l << 9) + k0]);
            c1a += pl * b2f(Es[(l << 9) + k1]);
        }
        m = mc;
    }
    const float inv = 1.0f / d;
    ctxb[((size_t)b << 9) + k0] = f2b(c0a * inv);
    ctxb[((size_t)b << 9) + k1] = f2b(c1a * inv);
}

// One-time (per call) weight conversion fp32->bf16, bias fusion, x padding to K=64.
__global__ __launch_bounds__(256) void prep_kernel(
    const float* __restrict__ x,
    const float* __restrict__ Wih0, const float* __restrict__ Whh0,
    const float* __restrict__ bih0, const float* __restrict__ bhh0,
    const float* __restrict__ Wih1, const float* __restrict__ Whh1,
    const float* __restrict__ bih1, const float* __restrict__ bhh1,
    const float* __restrict__ Wdih, const float* __restrict__ Wdhh,
    const float* __restrict__ bihd, const float* __restrict__ bhhd,
    u16* Wih0p, u16* Whh0b, u16* Wih1b, u16* Whh1b, u16* Wdihb, u16* Wdhhb,
    float* w0col, float* bias0, float* bias1, float* biasd, u16* xpad)
{
    const long E0 = 131072;
    const long E1 = E0 + 1048576;
    const long E2 = E1 + 1048576;
    const long E3 = E2 + 1048576;
    const long E4 = E3 + 1048576;
    const long E5 = E4 + 1048576;
    const long E6 = E5 + 2048;
    const long E7 = E6 + 2048;
    const long E8 = E7 + 2048;
    const long E9 = E8 + 2048;
    const long E10 = E9 + (long)B_ * L_ * KC;
    for (long idx = (long)blockIdx.x * 256 + threadIdx.x; idx < E10;
         idx += (long)gridDim.x * 256) {
        if (idx < E0) {
            long r = idx >> 6, cc = idx & 63;
            Wih0p[idx] = f2b(cc < NIN ? Wih0[(r << 3) + cc] : 0.0f);
        } else if (idx < E1) { long j = idx - E0; Whh0b[j] = f2b(Whh0[j]);
        } else if (idx < E2) { long j = idx - E1; Wih1b[j] = f2b(Wih1[j]);
        } else if (idx < E3) { long j = idx - E2; Whh1b[j] = f2b(Whh1[j]);
        } else if (idx < E4) {
            long j = idx - E3; long r = j >> 9, cc = j & 511;
            Wdihb[j] = f2b(Wdih[r * 513 + 1 + cc]);
        } else if (idx < E5) { long j = idx - E4; Wdhhb[j] = f2b(Wdhh[j]);
        } else if (idx < E6) { long j = idx - E5; w0col[j] = Wdih[j * 513];
        } else if (idx < E7) { long j = idx - E6; bias0[j] = bih0[j] + bhh0[j];
        } else if (idx < E8) { long j = idx - E7; bias1[j] = bih1[j] + bhh1[j];
        } else if (idx < E9) { long j = idx - E8; biasd[j] = bihd[j] + bhhd[j];
        } else {
            long j = idx - E9;
            long b = j / (L_ * KC);
            long rest = j - b * (L_ * KC);
            long l = rest >> 6, n = rest & 63;
            xpad[j] = f2b(n < NIN ? x[(b * L_ + l) * NIN + n] : 0.0f);
        }
    }
}

extern "C" void kernel_launch(void* const* d_in, const int* in_sizes, int n_in,
                              void* d_out, int out_size, void* d_ws, size_t ws_size,
                              hipStream_t stream)
{
    (void)in_sizes; (void)n_in; (void)out_size; (void)ws_size;
    const float* x    = (const float*)d_in[0];
    const float* Wih0 = (const float*)d_in[1];
    const float* Whh0 = (const float*)d_in[2];
    const float* bih0 = (const float*)d_in[3];
    const float* bhh0 = (const float*)d_in[4];
    const float* Wih1 = (const float*)d_in[5];
    const float* Whh1 = (const float*)d_in[6];
    const float* bih1 = (const float*)d_in[7];
    const float* bhh1 = (const float*)d_in[8];
    const float* Wdih = (const float*)d_in[9];
    const float* Wdhh = (const float*)d_in[10];
    const float* bihd = (const float*)d_in[11];
    const float* bhhd = (const float*)d_in[12];
    const float* Wfc  = (const float*)d_in[13];
    const float* bfc  = (const float*)d_in[14];
    float* out = (float*)d_out;

    char* ws = (char*)d_ws;
    float* c0    = (float*)(ws + 0);
    float* c1    = (float*)(ws + 524288);
    u16*   h0a   = (u16*)(ws + 1048576);
    u16*   h1a   = (u16*)(ws + 1310720);
    // zero region ends at 1572864
    u16*   h0b   = (u16*)(ws + 1572864);
    u16*   h1b   = (u16*)(ws + 1835008);
    float* h1fa  = (float*)(ws + 2097152);
    float* h1fb  = (float*)(ws + 2621440);
    u16*   ctxb  = (u16*)(ws + 3145728);
    float* ypv   = (float*)(ws + 3407872);
    u16*   Wih0p = (u16*)(ws + 3408896);
    u16*   Whh0b = (u16*)(ws + 3671040);
    u16*   Wih1b = (u16*)(ws + 5768192);
    u16*   Whh1b = (u16*)(ws + 7865344);
    u16*   Wdihb = (u16*)(ws + 9962496);
    u16*   Wdhhb = (u16*)(ws + 12059648);
    float* w0col = (float*)(ws + 14156800);
    float* bias0 = (float*)(ws + 14164992);
    float* bias1 = (float*)(ws + 14173184);
    float* biasd = (float*)(ws + 14181376);
    u16*   xpad  = (u16*)(ws + 14189568);
    u16*   E     = (u16*)(ws + 25199616);
    // total workspace use: 113,280,000 bytes

    hipMemsetAsync(d_ws, 0, 1572864, stream);  // c0, c1, h0[0], h1[0] = 0

    prep_kernel<<<512, 256, 0, stream>>>(x, Wih0, Whh0, bih0, bhh0,
        Wih1, Whh1, bih1, bhh1, Wdih, Wdhh, bihd, bhhd,
        Wih0p, Whh0b, Wih1b, Whh1b, Wdihb, Wdhhb, w0col, bias0, bias1, biasd, xpad);

    void* kargs[] = {
        (void*)&xpad,
        (void*)&Wih0p, (void*)&Whh0b, (void*)&bias0,
        (void*)&Wih1b, (void*)&Whh1b, (void*)&bias1,
        (void*)&h0a, (void*)&h0b, (void*)&c0,
        (void*)&h1a, (void*)&h1b, (void*)&h1fa, (void*)&h1fb, (void*)&c1,
        (void*)&E,
        (void*)&Wdihb, (void*)&Wdhhb, (void*)&biasd, (void*)&w0col,
        (void*)&ctxb, (void*)&ypv,
        (void*)&Wfc, (void*)&bfc,
        (void*)&out
    };
    hipError_t rc = hipLaunchCooperativeKernel(fused_kernel, dim3(256), dim3(256),
                                               kargs, 0, stream);
    if (rc != hipSuccess) {
        // co-residency validation failed -> verified multi-launch path
        (void)hipGetLastError();   // clear sticky error
        for (int tau = 0; tau <= L_; ++tau)
            enc_step_kernel<<<256, 256, 0, stream>>>(xpad, Wih0p, Whh0b, bias0,
                Wih1b, Whh1b, bias1, h0a, h0b, c0, h1a, h1b, h1fa, h1fb, c1, E, tau);
        for (int t = 0; t < PL_; ++t) {
            attn_step_kernel<<<256, 256, 0, stream>>>((t & 1) ? h1fb : h1fa, E,
                Wfc, bfc, ctxb, ypv, out, t);
            dec_step_kernel<<<128, 256, 0, stream>>>(ctxb, ypv, Wdihb, Wdhhb,
                biasd, w0col, h1a, h1b, h1fa, h1fb, c1, t);
        }
        attn_step_kernel<<<256, 256, 0, stream>>>(h1fa, E, Wfc, bfc, ctxb, ypv, out, PL_);
    }
}

// Round 4
// 17932.111 us; speedup vs baseline: 1.5677x; 1.5677x over previous
//
#include <hip/hip_runtime.h>
#include <hip/hip_bf16.h>

#define B_   256
#define L_   336
#define NIN  8
#define H_   512
#define PL_  96
#define KC   64
#define BT   32
#define GT   128

typedef unsigned short u16;
typedef __attribute__((ext_vector_type(8))) short short8;
typedef __attribute__((ext_vector_type(4))) float f32x4;

__device__ __forceinline__ float sigm(float x)   { return 1.0f / (1.0f + __expf(-x)); }
__device__ __forceinline__ float tanhf_(float x) { return 1.0f - 2.0f / (1.0f + __expf(2.0f * x)); }
__device__ __forceinline__ u16 f2b(float f) {
    __hip_bfloat16 h = __float2bfloat16(f);
    return __builtin_bit_cast(u16, h);
}
__device__ __forceinline__ float b2f(u16 u) {
    union { unsigned int i; float f; } v; v.i = ((unsigned int)u) << 16; return v.f;
}

// ============================ fused persistent path ============================

// Per-group (32-block) sense-reversing barrier. Data flow is batch-partitioned:
// group g = blocks {bid<128: bid&7==g} ∪ {bid>=128: (bid-128)&7==g}; all h/E/ctx/ypv
// traffic stays inside the group, so no 256-block sync is ever needed.
// Arrival RMW is ACQ_REL (release of this block's writes; extends release sequence);
// spin is RELAXED agent loads (sc1, no inv side effects) + s_sleep backoff;
// one acquire fence on exit. Read-read coherence on gen makes the epoch read safe.
__device__ __forceinline__ void group_barrier(unsigned* cnt, unsigned* gen) {
    __syncthreads();
    if (threadIdx.x == 0) {
        const unsigned g0 = __hip_atomic_load(gen, __ATOMIC_RELAXED, __HIP_MEMORY_SCOPE_AGENT);
        const unsigned a  = __hip_atomic_fetch_add(cnt, 1u, __ATOMIC_ACQ_REL, __HIP_MEMORY_SCOPE_AGENT);
        if (a == 31u) {
            __hip_atomic_store(cnt, 0u, __ATOMIC_RELAXED, __HIP_MEMORY_SCOPE_AGENT);
            __hip_atomic_store(gen, g0 + 1u, __ATOMIC_RELEASE, __HIP_MEMORY_SCOPE_AGENT);
        } else {
            while (__hip_atomic_load(gen, __ATOMIC_RELAXED, __HIP_MEMORY_SCOPE_AGENT) == g0)
                __builtin_amdgcn_s_sleep(2);
        }
        __threadfence();   // acquire: drop stale cached copies before reading peers' data
    }
    __syncthreads();
}

// A-panel: 32 batch rows x up-to-512 K elems, +8 pad => row stride 1040 B
struct EncSM {
    u16   in_s[32][520];
    float g_s[128][33];
};
struct AttnSM {
    float hs[H_];
    float red[256];
    u16   Es[48 * H_];
    float scores[48];
};
union SMU { EncSM enc; AttnSM attn; };

// ---- register-weight MFMA over one staged segment (K = NK*32) ----
#define MFMA_SEG(NK, WB, KOFS)                                                              \
    _Pragma("unroll")                                                                       \
    for (int kc = 0; kc < (NK); ++kc) {                                                     \
        const int kk = (kc << 5) + klo;                                                     \
        short8 a0 = *(const short8*)&sm.enc.in_s[lane & 15][kk];                            \
        short8 a1 = *(const short8*)&sm.enc.in_s[16 + (lane & 15)][kk];                     \
        acc[0][0] = __builtin_amdgcn_mfma_f32_16x16x32_bf16(a0, WB[0][(KOFS) + kc], acc[0][0], 0, 0, 0); \
        acc[1][0] = __builtin_amdgcn_mfma_f32_16x16x32_bf16(a1, WB[0][(KOFS) + kc], acc[1][0], 0, 0, 0); \
        acc[0][1] = __builtin_amdgcn_mfma_f32_16x16x32_bf16(a0, WB[1][(KOFS) + kc], acc[0][1], 0, 0, 0); \
        acc[1][1] = __builtin_amdgcn_mfma_f32_16x16x32_bf16(a1, WB[1][(KOFS) + kc], acc[1][1], 0, 0, 0); \
    }

// C/D layout (m89-verified): col(n)=lane&15, row(m)=(lane>>4)*4+reg
#define WRITE_GS()                                                                          \
    _Pragma("unroll")                                                                       \
    for (int mt = 0; mt < 2; ++mt)                                                          \
    _Pragma("unroll")                                                                       \
    for (int nt = 0; nt < 2; ++nt) {                                                        \
        const int gi = (((wv << 1) + nt) << 4) + (lane & 15);                               \
        const int brow = (mt << 4) + ((lane >> 4) << 2);                                    \
        _Pragma("unroll")                                                                   \
        for (int r = 0; r < 4; ++r) sm.enc.g_s[gi][brow + r] = acc[mt][nt][r];              \
    }

// load a 16-chunk (K=512) weight slice into registers, fragment layout
#define LOAD_W16_OFS(WB, OFS, PTR)                                                          \
    _Pragma("unroll")                                                                       \
    for (int nt = 0; nt < 2; ++nt) {                                                        \
        const size_t row_ = (size_t)((wv << 9) + j0 + (nt << 4) + (lane & 15));             \
        _Pragma("unroll")                                                                   \
        for (int kc = 0; kc < 16; ++kc)                                                     \
            WB[nt][(OFS) + kc] = *(const short8*)((PTR) + (row_ << 9) + (kc << 5) + klo);   \
    }

__device__ __forceinline__ void stage_h(EncSM& e, const u16* __restrict__ src,
                                        int batch0, int tid) {
    #pragma unroll
    for (int i = 0; i < 8; ++i) {
        const int idx = tid + (i << 8);
        const int row = idx >> 6, kq = idx & 63;
        *(uint4*)&e.in_s[row][kq << 3] =
            *(const uint4*)(src + ((size_t)(batch0 + row) << 9) + (kq << 3));
    }
}

__device__ __forceinline__ void cell_phase(EncSM& e,
    const float* __restrict__ bias, const float* __restrict__ w0col,
    const float* __restrict__ yprev, float* __restrict__ cbuf,
    u16* __restrict__ hbf_out, float* __restrict__ hf_out,
    u16* __restrict__ Ebuf, int te, int batch0, int j0, int tid)
{
    #pragma unroll
    for (int eix = 0; eix < 4; ++eix) {
        const int idx = tid + (eix << 8);
        const int b = idx >> 5, j = idx & 31;
        const int bg = batch0 + b, jg = j0 + j;
        float pre[4];
        #pragma unroll
        for (int q = 0; q < 4; ++q) {
            const int r = (q << 9) + jg;
            float v = e.g_s[(q << 5) + j][b] + bias[r];
            if (w0col) v += yprev[bg] * w0col[r];
            pre[q] = v;
        }
        const float iv = sigm(pre[0]);
        const float fv = sigm(pre[1]);
        const float gv = tanhf_(pre[2]);
        const float ov = sigm(pre[3]);
        const size_t ci = ((size_t)bg << 9) + jg;
        const float cold = cbuf[ci];
        const float cn = fv * cold + iv * gv;
        const float hn = ov * tanhf_(cn);
        cbuf[ci] = cn;
        hbf_out[ci] = f2b(hn);
        if (hf_out) hf_out[ci] = hn;
        if (Ebuf) Ebuf[((size_t)bg * L_ + te) * H_ + jg] = f2b(hn);
    }
}

// one recurrent step over two K=512 segments with register weights;
// segment-1 global loads issued before segment-0 MFMAs (T14 split).
__device__ __forceinline__ void step2seg(SMU& sm, const short8 (&wB)[2][32],
    const u16* __restrict__ src0, const u16* __restrict__ src1,
    const float* __restrict__ bias, const float* __restrict__ w0col,
    const float* __restrict__ yprev, float* __restrict__ cbuf,
    u16* __restrict__ hbf, float* __restrict__ hf, u16* __restrict__ Ebuf, int te,
    int batch0, int j0, int tid, int wv, int lane, int klo)
{
    __syncthreads();
    stage_h(sm.enc, src0, batch0, tid);
    uint4 pre2[8];
    #pragma unroll
    for (int i = 0; i < 8; ++i) {
        const int idx = tid + (i << 8);
        pre2[i] = *(const uint4*)(src1 + ((size_t)(batch0 + (idx >> 6)) << 9) + ((idx & 63) << 3));
    }
    __syncthreads();
    f32x4 acc[2][2] = {};
    MFMA_SEG(16, wB, 0);
    __syncthreads();
    #pragma unroll
    for (int i = 0; i < 8; ++i) {
        const int idx = tid + (i << 8);
        *(uint4*)&sm.enc.in_s[idx >> 6][(idx & 63) << 3] = pre2[i];
    }
    __syncthreads();
    MFMA_SEG(16, wB, 16);
    WRITE_GS();
    __syncthreads();
    cell_phase(sm.enc, bias, w0col, yprev, cbuf, hbf, hf, Ebuf, te, batch0, j0, tid);
}

// y_{step-1} = h.Wfc + b, then flash-style attention over E with one-tile
// register prefetch. step==PL_: y only.
__device__ __forceinline__ void attn_phase(SMU& sm,
    const float* __restrict__ hf, const u16* __restrict__ E,
    const float* __restrict__ Wfc, const float* __restrict__ bfc,
    u16* __restrict__ ctxb, float* __restrict__ yprev,
    float* __restrict__ out, int step, int b, int tid)
{
    AttnSM& a = sm.attn;
    const int wv = tid >> 6, lane = tid & 63;
    __syncthreads();
    a.hs[tid]       = hf[((size_t)b << 9) + tid];
    a.hs[tid + 256] = hf[((size_t)b << 9) + tid + 256];
    __syncthreads();
    float p = a.hs[tid] * Wfc[tid] + a.hs[tid + 256] * Wfc[tid + 256];
    a.red[tid] = p;
    __syncthreads();
    for (int s = 128; s > 0; s >>= 1) {
        if (tid < s) a.red[tid] += a.red[tid + s];
        __syncthreads();
    }
    if (tid == 0) {
        if (step > 0) {
            float y = a.red[0] + bfc[0];
            yprev[b] = y;
            out[b * PL_ + (step - 1)] = y;
        } else {
            yprev[b] = 0.0f;   // reference: y0 = zeros
        }
    }
    if (step == PL_) return;   // final: y only

    float m = -1e30f, d = 0.0f, c0a = 0.0f, c1a = 0.0f;
    const int k0 = tid, k1 = tid + 256;
    const uint4* Ebase = (const uint4*)(E + (((size_t)b * L_) << 9));
    uint4 pre[12];
    #pragma unroll
    for (int i = 0; i < 12; ++i) pre[i] = Ebase[tid + (i << 8)];

    for (int l0 = 0; l0 < L_; l0 += 48) {
        __syncthreads();
        {
            uint4* dst = (uint4*)a.Es;
            #pragma unroll
            for (int i = 0; i < 12; ++i) dst[tid + (i << 8)] = pre[i];
        }
        __syncthreads();
        if (l0 + 48 < L_) {
            const uint4* nx = Ebase + ((size_t)(l0 + 48) << 6);
            #pragma unroll
            for (int i = 0; i < 12; ++i) pre[i] = nx[tid + (i << 8)];
        }
        #pragma unroll
        for (int s = 0; s < 12; ++s) {
            const int l = wv * 12 + s;
            const u16* er = &a.Es[(l << 9) + (lane << 3)];
            float acc = 0.f;
            #pragma unroll
            for (int j = 0; j < 8; ++j)
                acc += a.hs[(lane << 3) + j] * b2f(er[j]);
            #pragma unroll
            for (int off = 32; off > 0; off >>= 1)
                acc += __shfl_xor(acc, off);
            if (lane == 0) a.scores[l] = acc;
        }
        __syncthreads();
        float mc = m;
        #pragma unroll
        for (int l = 0; l < 48; ++l) mc = fmaxf(mc, a.scores[l]);
        const float alpha = __expf(m - mc);
        d *= alpha; c0a *= alpha; c1a *= alpha;
        for (int l = 0; l < 48; ++l) {
            const float pl = __expf(a.scores[l] - mc);
            d += pl;
            c0a += pl * b2f(a.Es[(l << 9) + k0]);
            c1a += pl * b2f(a.Es[(l << 9) + k1]);
        }
        m = mc;
    }
    const float inv = 1.0f / d;
    ctxb[((size_t)b << 9) + k0] = f2b(c0a * inv);
    ctxb[((size_t)b << 9) + k1] = f2b(c1a * inv);
}

// Persistent kernel with per-group barriers. blocks 0..127: L0 role (then
// decoder cell); 128..255: L1 role. group g = batch tile g (32 rows).
// attn worker row = g*32 + pos (L0) / g*32 + 16 + pos (L1) — intra-group.
__global__ __launch_bounds__(256, 1) void fused_kernel(
    const u16* __restrict__ xpad,
    const u16* __restrict__ Wih0p, const u16* __restrict__ Whh0b, const float* __restrict__ bias0,
    const u16* __restrict__ Wih1b, const u16* __restrict__ Whh1b, const float* __restrict__ bias1,
    u16* __restrict__ h0a, u16* __restrict__ h0b, float* __restrict__ c0,
    u16* __restrict__ h1a, u16* __restrict__ h1b,
    float* __restrict__ h1f, float* __restrict__ c1,
    u16* __restrict__ E,
    const u16* __restrict__ Wdihb, const u16* __restrict__ Wdhhb,
    const float* __restrict__ biasd, const float* __restrict__ w0col,
    u16* __restrict__ ctxb, float* __restrict__ ypv,
    const float* __restrict__ Wfc, const float* __restrict__ bfc,
    float* __restrict__ out, unsigned* __restrict__ bar)
{
    __shared__ SMU sm;
    const int tid = threadIdx.x;
    const int bid = blockIdx.x;
    const int wv = tid >> 6, lane = tid & 63;
    const int klo = (lane >> 4) << 3;

    const int role = (bid < 128) ? 0 : 1;
    const int id   = role ? (bid - 128) : bid;
    const int g    = id & 7;
    const int pos  = id >> 3;
    const int batch0 = g << 5;
    const int j0     = pos << 5;
    const int myrow  = (g << 5) + (role ? 16 + pos : pos);
    unsigned* bcnt = bar + (g << 6);        // 256 B per group
    unsigned* bgen = bar + (g << 6) + 32;   // separate 128-B line

    if (role == 0) {
        {   // ---------------- encoder layer 0 ----------------
            short8 wB[2][18];           // K=64 (x) + K=512 (h) fragments
            #pragma unroll
            for (int nt = 0; nt < 2; ++nt) {
                const size_t row_ = (size_t)((wv << 9) + j0 + (nt << 4) + (lane & 15));
                wB[nt][0] = *(const short8*)(Wih0p + (row_ << 6) + klo);
                wB[nt][1] = *(const short8*)(Wih0p + (row_ << 6) + 32 + klo);
            }
            LOAD_W16_OFS(wB, 2, Whh0b);
            for (int tau = 0; tau <= L_; ++tau) {
                if (tau < L_) {
                    __syncthreads();
                    {   // stage x_t (32 x 64)
                        const int row = tid >> 3, kq = tid & 7;
                        *(uint4*)&sm.enc.in_s[row][kq << 3] =
                            *(const uint4*)(xpad + ((size_t)(batch0 + row) * L_ + tau) * KC + (kq << 3));
                    }
                    uint4 pre2[8];
                    {   // prefetch h0 prev while x-MFMA runs
                        const u16* src1 = (tau & 1) ? h0b : h0a;
                        #pragma unroll
                        for (int i = 0; i < 8; ++i) {
                            const int idx = tid + (i << 8);
                            pre2[i] = *(const uint4*)(src1 + ((size_t)(batch0 + (idx >> 6)) << 9) + ((idx & 63) << 3));
                        }
                    }
                    __syncthreads();
                    f32x4 acc[2][2] = {};
                    MFMA_SEG(2, wB, 0);
                    __syncthreads();
                    #pragma unroll
                    for (int i = 0; i < 8; ++i) {
                        const int idx = tid + (i << 8);
                        *(uint4*)&sm.enc.in_s[idx >> 6][(idx & 63) << 3] = pre2[i];
                    }
                    __syncthreads();
                    MFMA_SEG(16, wB, 2);
                    WRITE_GS();
                    __syncthreads();
                    cell_phase(sm.enc, bias0, nullptr, nullptr, c0,
                               (tau & 1) ? h0a : h0b, nullptr, nullptr, 0,
                               batch0, j0, tid);
                }
                group_barrier(bcnt, bgen);
            }
        }
        {   // ---------------- decoder: attention + cell ----------------
            short8 wB[2][32];
            LOAD_W16_OFS(wB, 0, Wdihb);
            LOAD_W16_OFS(wB, 16, Wdhhb);
            for (int t = 0; t < PL_; ++t) {
                attn_phase(sm, h1f, E, Wfc, bfc, ctxb, ypv, out, t, myrow, tid);
                group_barrier(bcnt, bgen);
                step2seg(sm, wB, ctxb, (t & 1) ? h1b : h1a,
                         biasd, w0col, ypv, c1,
                         (t & 1) ? h1a : h1b, h1f, nullptr, 0,
                         batch0, j0, tid, wv, lane, klo);
                group_barrier(bcnt, bgen);
            }
        }
        attn_phase(sm, h1f, E, Wfc, bfc, ctxb, ypv, out, PL_, myrow, tid);
    } else {
        {   // ---------------- encoder layer 1 (one step behind) ----------------
            short8 wB[2][32];
            LOAD_W16_OFS(wB, 0, Wih1b);
            LOAD_W16_OFS(wB, 16, Whh1b);
            for (int tau = 0; tau <= L_; ++tau) {
                if (tau >= 1) {
                    const int te = tau - 1;
                    step2seg(sm, wB,
                             (tau & 1) ? h0b : h0a,            // ys0[te]
                             (te & 1) ? h1b : h1a,             // h1 prev
                             bias1, nullptr, nullptr, c1,
                             (te & 1) ? h1a : h1b, h1f, E, te,
                             batch0, j0, tid, wv, lane, klo);
                }
                group_barrier(bcnt, bgen);
            }
        }
        for (int t = 0; t < PL_; ++t) {
            attn_phase(sm, h1f, E, Wfc, bfc, ctxb, ypv, out, t, myrow, tid);
            group_barrier(bcnt, bgen);
            group_barrier(bcnt, bgen);   // cell phase runs on L0-role blocks
        }
        attn_phase(sm, h1f, E, Wfc, bfc, ctxb, ypv, out, PL_, myrow, tid);
    }
}

// ===================== verified multi-launch fallback path =====================

struct Seg { const u16* src; int stride; const u16* W; int nch; int ldw; };

struct SMOld {
    u16   in_s[BT][KC + 8];
    u16   w_s[GT][KC + 8];
    float g_s[GT][BT + 1];
};

__device__ void gates_gemm_cell(const Seg* segs,
    const float* __restrict__ bias, const float* __restrict__ w0col,
    const float* __restrict__ yprev,
    float* __restrict__ cbuf, u16* __restrict__ hbf_out, float* __restrict__ hf_out,
    u16* __restrict__ Ebuf, int te, int batch0, int j0, SMOld& sm)
{
    const int tid = threadIdx.x;
    const int wv = tid >> 6, lane = tid & 63;
    f32x4 acc[2][2] = {};

    for (int s = 0; s < 2; ++s) {
        const Seg sg = segs[s];
        for (int c = 0; c < sg.nch; ++c) {
            const int k0 = c * KC;
            __syncthreads();
            {
                const int b = tid >> 3, kq = tid & 7;
                const uint4* p = (const uint4*)(sg.src + (size_t)(batch0 + b) * sg.stride + k0) + kq;
                *(uint4*)&sm.in_s[b][kq << 3] = *p;
            }
            #pragma unroll
            for (int i = 0; i < 4; ++i) {
                const int idx = tid + (i << 8);
                const int gi = idx >> 3, kq = idx & 7;
                const int row = ((gi >> 5) << 9) + j0 + (gi & 31);
                const uint4* p = (const uint4*)(sg.W + (size_t)row * sg.ldw + k0) + kq;
                *(uint4*)&sm.w_s[gi][kq << 3] = *p;
            }
            __syncthreads();
            #pragma unroll
            for (int ks = 0; ks < 2; ++ks) {
                const int kk = (ks << 5) + ((lane >> 4) << 3);
                short8 a0 = *(const short8*)&sm.in_s[lane & 15][kk];
                short8 a1 = *(const short8*)&sm.in_s[16 + (lane & 15)][kk];
                #pragma unroll
                for (int nt = 0; nt < 2; ++nt) {
                    const int gi = (((wv << 1) + nt) << 4) + (lane & 15);
                    short8 bb = *(const short8*)&sm.w_s[gi][kk];
                    acc[0][nt] = __builtin_amdgcn_mfma_f32_16x16x32_bf16(a0, bb, acc[0][nt], 0, 0, 0);
                    acc[1][nt] = __builtin_amdgcn_mfma_f32_16x16x32_bf16(a1, bb, acc[1][nt], 0, 0, 0);
                }
            }
        }
    }
    __syncthreads();
    #pragma unroll
    for (int mt = 0; mt < 2; ++mt)
        #pragma unroll
        for (int nt = 0; nt < 2; ++nt) {
            const int gi = (((wv << 1) + nt) << 4) + (lane & 15);
            const int brow = (mt << 4) + ((lane >> 4) << 2);
            #pragma unroll
            for (int r = 0; r < 4; ++r)
                sm.g_s[gi][brow + r] = acc[mt][nt][r];
        }
    __syncthreads();

    #pragma unroll
    for (int e = 0; e < 4; ++e) {
        const int idx = tid + (e << 8);
        const int b = idx >> 5, j = idx & 31;
        const int bg = batch0 + b, jg = j0 + j;
        float pre[4];
        #pragma unroll
        for (int q = 0; q < 4; ++q) {
            const int r = (q << 9) + jg;
            float v = sm.g_s[(q << 5) + j][b] + bias[r];
            if (w0col) v += yprev[bg] * w0col[r];
            pre[q] = v;
        }
        const float iv = sigm(pre[0]);
        const float fv = sigm(pre[1]);
        const float gv = tanhf_(pre[2]);
        const float ov = sigm(pre[3]);
        const size_t ci = ((size_t)bg << 9) + jg;
        const float cold = cbuf[ci];
        const float cn = fv * cold + iv * gv;
        const float hn = ov * tanhf_(cn);
        cbuf[ci] = cn;
        hbf_out[ci] = f2b(hn);
        if (hf_out) hf_out[ci] = hn;
        if (Ebuf) Ebuf[((size_t)bg * L_ + te) * H_ + jg] = f2b(hn);
    }
}

__global__ __launch_bounds__(256) void enc_step_kernel(
    const u16* __restrict__ xpad, const u16* __restrict__ Wih0p, const u16* __restrict__ Whh0b,
    const float* __restrict__ bias0,
    const u16* __restrict__ Wih1b, const u16* __restrict__ Whh1b, const float* __restrict__ bias1,
    u16* h0a, u16* h0b, float* c0,
    u16* h1a, u16* h1b, float* h1fa, float* h1fb, float* c1,
    u16* E, int tau)
{
    __shared__ SMOld sm;
    const int bid = blockIdx.x;
    if (bid < 128) {
        if (tau >= L_) return;
        const int tb = bid & 7, th = bid >> 3;
        Seg segs[2];
        segs[0] = { xpad + tau * KC, L_ * KC, Wih0p, 1, KC };
        segs[1] = { (tau & 1) ? h0b : h0a, H_, Whh0b, 8, H_ };
        gates_gemm_cell(segs, bias0, nullptr, nullptr, c0,
                        (tau & 1) ? h0a : h0b, nullptr, nullptr, 0,
                        tb * BT, th * 32, sm);
    } else {
        if (tau == 0) return;
        const int te = tau - 1;
        const int id = bid - 128;
        const int tb = id & 7, th = id >> 3;
        Seg segs[2];
        segs[0] = { (tau & 1) ? h0b : h0a, H_, Wih1b, 8, H_ };
        segs[1] = { (te & 1) ? h1b : h1a, H_, Whh1b, 8, H_ };
        gates_gemm_cell(segs, bias1, nullptr, nullptr, c1,
                        (te & 1) ? h1a : h1b, (te & 1) ? h1fa : h1fb, E, te,
                        tb * BT, th * 32, sm);
    }
}

__global__ __launch_bounds__(256) void dec_step_kernel(
    const u16* __restrict__ ctxb, const float* __restrict__ yprev,
    const u16* __restrict__ Wdihb, const u16* __restrict__ Wdhhb,
    const float* __restrict__ biasd, const float* __restrict__ w0col,
    u16* h1a, u16* h1b, float* h1fa, float* h1fb, float* c1, int t)
{
    __shared__ SMOld sm;
    const int bid = blockIdx.x;
    const int tb = bid & 7, th = bid >> 3;
    Seg segs[2];
    segs[0] = { ctxb, H_, Wdihb, 8, H_ };
    segs[1] = { (t & 1) ? h1b : h1a, H_, Wdhhb, 8, H_ };
    gates_gemm_cell(segs, biasd, w0col, yprev, c1,
                    (t & 1) ? h1a : h1b, (t & 1) ? h1fa : h1fb, nullptr, 0,
                    tb * BT, th * 32, sm);
}

__global__ __launch_bounds__(256) void attn_step_kernel(
    const float* __restrict__ hf, const u16* __restrict__ E,
    const float* __restrict__ Wfc, const float* __restrict__ bfc,
    u16* __restrict__ ctxb, float* __restrict__ yprev,
    float* __restrict__ out, int step)
{
    __shared__ float hs[H_];
    __shared__ float red[256];
    __shared__ u16 Es[48 * H_];
    __shared__ float scores[48];
    const int tid = threadIdx.x;
    const int b = blockIdx.x;

    hs[tid]       = hf[((size_t)b << 9) + tid];
    hs[tid + 256] = hf[((size_t)b << 9) + tid + 256];
    __syncthreads();

    float p = hs[tid] * Wfc[tid] + hs[tid + 256] * Wfc[tid + 256];
    red[tid] = p;
    __syncthreads();
    for (int s = 128; s > 0; s >>= 1) {
        if (tid < s) red[tid] += red[tid + s];
        __syncthreads();
    }
    if (tid == 0) {
        if (step > 0) {
            float y = red[0] + bfc[0];
            yprev[b] = y;
            out[b * PL_ + (step - 1)] = y;
        } else {
            yprev[b] = 0.0f;
        }
    }
    if (step == PL_) return;

    const int wv = tid >> 6, lane = tid & 63;
    float m = -1e30f, d = 0.0f, c0a = 0.0f, c1a = 0.0f;
    const int k0 = tid, k1 = tid + 256;

    for (int l0 = 0; l0 < L_; l0 += 48) {
        __syncthreads();
        {
            const uint4* src = (const uint4*)(E + (((size_t)b * L_ + l0) << 9));
            uint4* dst = (uint4*)Es;
            #pragma unroll
            for (int i = 0; i < 12; ++i)
                dst[tid + (i << 8)] = src[tid + (i << 8)];
        }
        __syncthreads();
        #pragma unroll
        for (int s = 0; s < 12; ++s) {
            const int l = wv * 12 + s;
            const u16* er = &Es[(l << 9) + (lane << 3)];
            float acc = 0.f;
            #pragma unroll
            for (int j = 0; j < 8; ++j)
                acc += hs[(lane << 3) + j] * b2f(er[j]);
            #pragma unroll
            for (int off = 32; off > 0; off >>= 1)
                acc += __shfl_xor(acc, off);
            if (lane == 0) scores[l] = acc;
        }
        __syncthreads();
        float mc = m;
        #pragma unroll
        for (int l = 0; l < 48; ++l) mc = fmaxf(mc, scores[l]);
        const float alpha = __expf(m - mc);
        d *= alpha; c0a *= alpha; c1a *= alpha;
        for (int l = 0; l < 48; ++l) {
            const float pl = __expf(scores[l] - mc);
            d += pl;
            c0a += pl * b2f(Es[(l << 9) + k0]);
            c1a += pl * b2f(Es[(l << 9) + k1]);
        }
        m = mc;
    }
    const float inv = 1.0f / d;
    ctxb[((size_t)b << 9) + k0] = f2b(c0a * inv);
    ctxb[((size_t)b << 9) + k1] = f2b(c1a * inv);
}

// One-time (per call) weight conversion fp32->bf16, bias fusion, x padding to K=64.
__global__ __launch_bounds__(256) void prep_kernel(
    const float* __restrict__ x,
    const float* __restrict__ Wih0, const float* __restrict__ Whh0,
    const float* __restrict__ bih0, const float* __restrict__ bhh0,
    const float* __restrict__ Wih1, const float* __restrict__ Whh1,
    const float* __restrict__ bih1, const float* __restrict__ bhh1,
    const float* __restrict__ Wdih, const float* __restrict__ Wdhh,
    const float* __restrict__ bihd, const float* __restrict__ bhhd,
    u16* Wih0p, u16* Whh0b, u16* Wih1b, u16* Whh1b, u16* Wdihb, u16* Wdhhb,
    float* w0col, float* bias0, float* bias1, float* biasd, u16* xpad)
{
    const long E0 = 131072;
    const long E1 = E0 + 1048576;
    const long E2 = E1 + 1048576;
    const long E3 = E2 + 1048576;
    const long E4 = E3 + 1048576;
    const long E5 = E4 + 1048576;
    const long E6 = E5 + 2048;
    const long E7 = E6 + 2048;
    const long E8 = E7 + 2048;
    const long E9 = E8 + 2048;
    const long E10 = E9 + (long)B_ * L_ * KC;
    for (long idx = (long)blockIdx.x * 256 + threadIdx.x; idx < E10;
         idx += (long)gridDim.x * 256) {
        if (idx < E0) {
            long r = idx >> 6, cc = idx & 63;
            Wih0p[idx] = f2b(cc < NIN ? Wih0[(r << 3) + cc] : 0.0f);
        } else if (idx < E1) { long j = idx - E0; Whh0b[j] = f2b(Whh0[j]);
        } else if (idx < E2) { long j = idx - E1; Wih1b[j] = f2b(Wih1[j]);
        } else if (idx < E3) { long j = idx - E2; Whh1b[j] = f2b(Whh1[j]);
        } else if (idx < E4) {
            long j = idx - E3; long r = j >> 9, cc = j & 511;
            Wdihb[j] = f2b(Wdih[r * 513 + 1 + cc]);
        } else if (idx < E5) { long j = idx - E4; Wdhhb[j] = f2b(Wdhh[j]);
        } else if (idx < E6) { long j = idx - E5; w0col[j] = Wdih[j * 513];
        } else if (idx < E7) { long j = idx - E6; bias0[j] = bih0[j] + bhh0[j];
        } else if (idx < E8) { long j = idx - E7; bias1[j] = bih1[j] + bhh1[j];
        } else if (idx < E9) { long j = idx - E8; biasd[j] = bihd[j] + bhhd[j];
        } else {
            long j = idx - E9;
            long b = j / (L_ * KC);
            long rest = j - b * (L_ * KC);
            long l = rest >> 6, n = rest & 63;
            xpad[j] = f2b(n < NIN ? x[(b * L_ + l) * NIN + n] : 0.0f);
        }
    }
}

extern "C" void kernel_launch(void* const* d_in, const int* in_sizes, int n_in,
                              void* d_out, int out_size, void* d_ws, size_t ws_size,
                              hipStream_t stream)
{
    (void)in_sizes; (void)n_in; (void)out_size; (void)ws_size;
    const float* x    = (const float*)d_in[0];
    const float* Wih0 = (const float*)d_in[1];
    const float* Whh0 = (const float*)d_in[2];
    const float* bih0 = (const float*)d_in[3];
    const float* bhh0 = (const float*)d_in[4];
    const float* Wih1 = (const float*)d_in[5];
    const float* Whh1 = (const float*)d_in[6];
    const float* bih1 = (const float*)d_in[7];
    const float* bhh1 = (const float*)d_in[8];
    const float* Wdih = (const float*)d_in[9];
    const float* Wdhh = (const float*)d_in[10];
    const float* bihd = (const float*)d_in[11];
    const float* bhhd = (const float*)d_in[12];
    const float* Wfc  = (const float*)d_in[13];
    const float* bfc  = (const float*)d_in[14];
    float* out = (float*)d_out;

    char* ws = (char*)d_ws;
    float* c0    = (float*)(ws + 0);
    float* c1    = (float*)(ws + 524288);
    u16*   h0a   = (u16*)(ws + 1048576);
    u16*   h1a   = (u16*)(ws + 1310720);
    // zero region ends at 1572864
    u16*   h0b   = (u16*)(ws + 1572864);
    u16*   h1b   = (u16*)(ws + 1835008);
    float* h1fa  = (float*)(ws + 2097152);      // fused path: the single h1f
    unsigned* bar = (unsigned*)(ws + 2621440);  // 2 KB barrier flags (old h1fb slot)
    float* h1fb  = (float*)(ws + 2621440);      // fallback path only
    u16*   ctxb  = (u16*)(ws + 3145728);
    float* ypv   = (float*)(ws + 3407872);
    u16*   Wih0p = (u16*)(ws + 3408896);
    u16*   Whh0b = (u16*)(ws + 3671040);
    u16*   Wih1b = (u16*)(ws + 5768192);
    u16*   Whh1b = (u16*)(ws + 7865344);
    u16*   Wdihb = (u16*)(ws + 9962496);
    u16*   Wdhhb = (u16*)(ws + 12059648);
    float* w0col = (float*)(ws + 14156800);
    float* bias0 = (float*)(ws + 14164992);
    float* bias1 = (float*)(ws + 14173184);
    float* biasd = (float*)(ws + 14181376);
    u16*   xpad  = (u16*)(ws + 14189568);
    u16*   E     = (u16*)(ws + 25199616);
    // total workspace use: 113,280,000 bytes (unchanged)

    hipMemsetAsync(d_ws, 0, 1572864, stream);       // c0, c1, h0[0], h1[0] = 0
    hipMemsetAsync(ws + 2621440, 0, 2048, stream);  // barrier flags = 0

    prep_kernel<<<512, 256, 0, stream>>>(x, Wih0, Whh0, bih0, bhh0,
        Wih1, Whh1, bih1, bhh1, Wdih, Wdhh, bihd, bhhd,
        Wih0p, Whh0b, Wih1b, Whh1b, Wdihb, Wdhhb, w0col, bias0, bias1, biasd, xpad);

    void* kargs[] = {
        (void*)&xpad,
        (void*)&Wih0p, (void*)&Whh0b, (void*)&bias0,
        (void*)&Wih1b, (void*)&Whh1b, (void*)&bias1,
        (void*)&h0a, (void*)&h0b, (void*)&c0,
        (void*)&h1a, (void*)&h1b, (void*)&h1fa, (void*)&c1,
        (void*)&E,
        (void*)&Wdihb, (void*)&Wdhhb, (void*)&biasd, (void*)&w0col,
        (void*)&ctxb, (void*)&ypv,
        (void*)&Wfc, (void*)&bfc,
        (void*)&out, (void*)&bar
    };
    hipError_t rc = hipLaunchCooperativeKernel(fused_kernel, dim3(256), dim3(256),
                                               kargs, 0, stream);
    if (rc != hipSuccess) {
        // co-residency validation failed -> verified multi-launch path
        (void)hipGetLastError();   // clear sticky error
        for (int tau = 0; tau <= L_; ++tau)
            enc_step_kernel<<<256, 256, 0, stream>>>(xpad, Wih0p, Whh0b, bias0,
                Wih1b, Whh1b, bias1, h0a, h0b, c0, h1a, h1b, h1fa, h1fb, c1, E, tau);
        for (int t = 0; t < PL_; ++t) {
            attn_step_kernel<<<256, 256, 0, stream>>>((t & 1) ? h1fb : h1fa, E,
                Wfc, bfc, ctxb, ypv, out, t);
            dec_step_kernel<<<128, 256, 0, stream>>>(ctxb, ypv, Wdihb, Wdhhb,
                biasd, w0col, h1a, h1b, h1fa, h1fb, c1, t);
        }
        attn_step_kernel<<<256, 256, 0, stream>>>(h1fa, E, Wfc, bfc, ctxb, ypv, out, PL_);
    }
}

// Round 7
// 14937.030 us; speedup vs baseline: 1.8820x; 1.2005x over previous
//
#include <hip/hip_runtime.h>
#include <hip/hip_bf16.h>

#define B_   256
#define L_   336
#define NIN  8
#define H_   512
#define PL_  96
#define KC   64
#define BT   32
#define GT   128

typedef unsigned short u16;
typedef unsigned long long u64;
typedef __attribute__((ext_vector_type(8))) short short8;
typedef __attribute__((ext_vector_type(4))) float f32x4;

__device__ __forceinline__ float sigm(float x)   { return 1.0f / (1.0f + __expf(-x)); }
__device__ __forceinline__ float tanhf_(float x) { return 1.0f - 2.0f / (1.0f + __expf(2.0f * x)); }
__device__ __forceinline__ u16 f2b(float f) {
    __hip_bfloat16 h = __float2bfloat16(f);
    return __builtin_bit_cast(u16, h);
}
__device__ __forceinline__ float b2f(u16 u) {
    union { unsigned int i; float f; } v; v.i = ((unsigned int)u) << 16; return v.f;
}

// Agent-scope (cross-XCD coherent, write-through) relaxed stores. These put
// shared state at the coherence point directly, so barriers need NO L2
// writeback (buffer_wbl2) — only an invalidate on the consumer side.
__device__ __forceinline__ void st_ag_u32(unsigned* p, unsigned v) {
    __hip_atomic_store(p, v, __ATOMIC_RELAXED, __HIP_MEMORY_SCOPE_AGENT);
}
__device__ __forceinline__ void st_ag_f32(float* p, float v) {
    __hip_atomic_store(p, v, __ATOMIC_RELAXED, __HIP_MEMORY_SCOPE_AGENT);
}
__device__ __forceinline__ void st_ag_u64(u64* p, u64 v) {
    __hip_atomic_store(p, v, __ATOMIC_RELAXED, __HIP_MEMORY_SCOPE_AGENT);
}

// ============================ fused persistent path ============================

// Per-group (32-block) barrier, wbl2-free:
//  - arrival: per-block flag store (relaxed sc1, AFTER __syncthreads' vmcnt
//    drain => all this block's sc1 data stores are at the coherence point)
//  - leader (me==0) polls all 32 flags with 32 lanes, publishes gen
//  - others poll gen (single line)
//  - exit: acquire fence (buffer_inv only — drop stale local L2 copies)
// No RMW, no serialization, no writeback walks.
__device__ __forceinline__ void group_barrier(unsigned* flags, unsigned ep, int me) {
    __syncthreads();                      // compiler drains vmcnt before s_barrier
    const int tid = threadIdx.x;
    if (tid < 64) {
        if (tid == 0) {
            asm volatile("s_waitcnt vmcnt(0)" ::: "memory");
            __hip_atomic_store(&flags[me << 4], ep, __ATOMIC_RELAXED, __HIP_MEMORY_SCOPE_AGENT);
        }
        if (me == 0) {
            for (;;) {
                unsigned v = __hip_atomic_load(&flags[(tid & 31) << 4],
                                               __ATOMIC_RELAXED, __HIP_MEMORY_SCOPE_AGENT);
                if (__all(v >= ep)) break;
                __builtin_amdgcn_s_sleep(1);
            }
            if (tid == 0)
                __hip_atomic_store(&flags[512], ep, __ATOMIC_RELAXED, __HIP_MEMORY_SCOPE_AGENT);
        } else if (tid == 0) {
            while (__hip_atomic_load(&flags[512], __ATOMIC_RELAXED, __HIP_MEMORY_SCOPE_AGENT) < ep)
                __builtin_amdgcn_s_sleep(1);
        }
        __builtin_amdgcn_fence(__ATOMIC_ACQUIRE, "agent");   // buffer_inv, no wb
    }
    __syncthreads();
}

// A-panel: 32 batch rows x up-to-512 K elems, +8 pad => row stride 1040 B
struct EncSM {
    u16   in_s[32][520];
    float g_s[128][33];
};
struct AttnSM {
    float hs[H_];
    float red[256];
    u16   Es[48 * H_];
    float scores[48];
};
union SMU { EncSM enc; AttnSM attn; };

// ---- register-weight MFMA over one staged segment (K = NK*32) ----
#define MFMA_SEG(NK, WB, KOFS)                                                              \
    _Pragma("unroll")                                                                       \
    for (int kc = 0; kc < (NK); ++kc) {                                                     \
        const int kk = (kc << 5) + klo;                                                     \
        short8 a0 = *(const short8*)&sm.enc.in_s[lane & 15][kk];                            \
        short8 a1 = *(const short8*)&sm.enc.in_s[16 + (lane & 15)][kk];                     \
        acc[0][0] = __builtin_amdgcn_mfma_f32_16x16x32_bf16(a0, WB[0][(KOFS) + kc], acc[0][0], 0, 0, 0); \
        acc[1][0] = __builtin_amdgcn_mfma_f32_16x16x32_bf16(a1, WB[0][(KOFS) + kc], acc[1][0], 0, 0, 0); \
        acc[0][1] = __builtin_amdgcn_mfma_f32_16x16x32_bf16(a0, WB[1][(KOFS) + kc], acc[0][1], 0, 0, 0); \
        acc[1][1] = __builtin_amdgcn_mfma_f32_16x16x32_bf16(a1, WB[1][(KOFS) + kc], acc[1][1], 0, 0, 0); \
    }

// C/D layout (m89-verified): col(n)=lane&15, row(m)=(lane>>4)*4+reg
#define WRITE_GS()                                                                          \
    _Pragma("unroll")                                                                       \
    for (int mt = 0; mt < 2; ++mt)                                                          \
    _Pragma("unroll")                                                                       \
    for (int nt = 0; nt < 2; ++nt) {                                                        \
        const int gi = (((wv << 1) + nt) << 4) + (lane & 15);                               \
        const int brow = (mt << 4) + ((lane >> 4) << 2);                                    \
        _Pragma("unroll")                                                                   \
        for (int r = 0; r < 4; ++r) sm.enc.g_s[gi][brow + r] = acc[mt][nt][r];              \
    }

// load a 16-chunk (K=512) weight slice into registers, fragment layout
#define LOAD_W16_OFS(WB, OFS, PTR)                                                          \
    _Pragma("unroll")                                                                       \
    for (int nt = 0; nt < 2; ++nt) {                                                        \
        const size_t row_ = (size_t)((wv << 9) + j0 + (nt << 4) + (lane & 15));             \
        _Pragma("unroll")                                                                   \
        for (int kc = 0; kc < 16; ++kc)                                                     \
            WB[nt][(OFS) + kc] = *(const short8*)((PTR) + (row_ << 9) + (kc << 5) + klo);   \
    }

__device__ __forceinline__ void stage_h(EncSM& e, const u16* __restrict__ src,
                                        int batch0, int tid) {
    #pragma unroll
    for (int i = 0; i < 8; ++i) {
        const int idx = tid + (i << 8);
        const int row = idx >> 6, kq = idx & 63;
        *(uint4*)&e.in_s[row][kq << 3] =
            *(const uint4*)(src + ((size_t)(batch0 + row) << 9) + (kq << 3));
    }
}

// LSTM cell epilogue: 512 j-pairs, 2/thread; all cross-block outputs written
// with agent-scope packed stores (u32 bf16-pair / u64 f32-pair).
__device__ __forceinline__ void cell_phase(EncSM& e,
    const float* __restrict__ bias, const float* __restrict__ w0col,
    const float* __restrict__ yprev, float* __restrict__ cbuf,
    u16* __restrict__ hbf_out, float* __restrict__ hf_out,
    u16* __restrict__ Ebuf, int te, int batch0, int j0, int tid)
{
    #pragma unroll
    for (int eix = 0; eix < 2; ++eix) {
        const int idx = tid + (eix << 8);          // 0..511
        const int b = idx >> 4, jp = idx & 15;
        const int j = jp << 1;
        const int bg = batch0 + b, jg = j0 + j;
        float cn2[2], hn2[2];
        const size_t ci = ((size_t)bg << 9) + jg;
        #pragma unroll
        for (int u = 0; u < 2; ++u) {
            float pre[4];
            #pragma unroll
            for (int q = 0; q < 4; ++q) {
                const int r = (q << 9) + jg + u;
                float v = e.g_s[(q << 5) + j + u][b] + bias[r];
                if (w0col) v += yprev[bg] * w0col[r];
                pre[q] = v;
            }
            const float iv = sigm(pre[0]);
            const float fv = sigm(pre[1]);
            const float gv = tanhf_(pre[2]);
            const float ov = sigm(pre[3]);
            const float cold = cbuf[ci + u];
            cn2[u] = fv * cold + iv * gv;
            hn2[u] = ov * tanhf_(cn2[u]);
        }
        // c crosses blocks at encoder->decoder handoff: sc1 too
        st_ag_u64((u64*)&cbuf[ci],
                  ((u64)__builtin_bit_cast(unsigned, cn2[1]) << 32) |
                  (u64)__builtin_bit_cast(unsigned, cn2[0]));
        st_ag_u32((unsigned*)&hbf_out[ci],
                  (unsigned)f2b(hn2[0]) | ((unsigned)f2b(hn2[1]) << 16));
        if (hf_out)
            st_ag_u64((u64*)&hf_out[ci],
                      ((u64)__builtin_bit_cast(unsigned, hn2[1]) << 32) |
                      (u64)__builtin_bit_cast(unsigned, hn2[0]));
        if (Ebuf)
            st_ag_u32((unsigned*)&Ebuf[((size_t)bg * L_ + te) * H_ + jg],
                      (unsigned)f2b(hn2[0]) | ((unsigned)f2b(hn2[1]) << 16));
    }
}

// one recurrent step over two K=512 segments with register weights;
// segment-1 global loads issued before segment-0 MFMAs (T14 split).
__device__ __forceinline__ void step2seg(SMU& sm, const short8 (&wB)[2][32],
    const u16* __restrict__ src0, const u16* __restrict__ src1,
    const float* __restrict__ bias, const float* __restrict__ w0col,
    const float* __restrict__ yprev, float* __restrict__ cbuf,
    u16* __restrict__ hbf, float* __restrict__ hf, u16* __restrict__ Ebuf, int te,
    int batch0, int j0, int tid, int wv, int lane, int klo)
{
    __syncthreads();
    stage_h(sm.enc, src0, batch0, tid);
    uint4 pre2[8];
    #pragma unroll
    for (int i = 0; i < 8; ++i) {
        const int idx = tid + (i << 8);
        pre2[i] = *(const uint4*)(src1 + ((size_t)(batch0 + (idx >> 6)) << 9) + ((idx & 63) << 3));
    }
    __syncthreads();
    f32x4 acc[2][2] = {};
    MFMA_SEG(16, wB, 0);
    __syncthreads();
    #pragma unroll
    for (int i = 0; i < 8; ++i) {
        const int idx = tid + (i << 8);
        *(uint4*)&sm.enc.in_s[idx >> 6][(idx & 63) << 3] = pre2[i];
    }
    __syncthreads();
    MFMA_SEG(16, wB, 16);
    WRITE_GS();
    __syncthreads();
    cell_phase(sm.enc, bias, w0col, yprev, cbuf, hbf, hf, Ebuf, te, batch0, j0, tid);
}

// y_{step-1} = h.Wfc + b, then flash-style attention over E with one-tile
// register prefetch. step==PL_: y only.
__device__ __forceinline__ void attn_phase(SMU& sm,
    const float* __restrict__ hf, const u16* __restrict__ E,
    const float* __restrict__ Wfc, const float* __restrict__ bfc,
    u16* __restrict__ ctxb, float* __restrict__ yprev,
    float* __restrict__ out, int step, int b, int tid)
{
    AttnSM& a = sm.attn;
    const int wv = tid >> 6, lane = tid & 63;
    __syncthreads();
    a.hs[tid]       = hf[((size_t)b << 9) + tid];
    a.hs[tid + 256] = hf[((size_t)b << 9) + tid + 256];
    __syncthreads();
    float p = a.hs[tid] * Wfc[tid] + a.hs[tid + 256] * Wfc[tid + 256];
    a.red[tid] = p;
    __syncthreads();
    for (int s = 128; s > 0; s >>= 1) {
        if (tid < s) a.red[tid] += a.red[tid + s];
        __syncthreads();
    }
    if (tid == 0) {
        if (step > 0) {
            float y = a.red[0] + bfc[0];
            st_ag_f32(&yprev[b], y);
            out[b * PL_ + (step - 1)] = y;     // host-read only: normal store
        } else {
            st_ag_f32(&yprev[b], 0.0f);        // reference: y0 = zeros
        }
    }
    if (step == PL_) return;   // final: y only

    float m = -1e30f, d = 0.0f, c0a = 0.0f, c1a = 0.0f;
    const int k0 = tid, k1 = tid + 256;
    const uint4* Ebase = (const uint4*)(E + (((size_t)b * L_) << 9));
    uint4 pre[12];
    #pragma unroll
    for (int i = 0; i < 12; ++i) pre[i] = Ebase[tid + (i << 8)];

    for (int l0 = 0; l0 < L_; l0 += 48) {
        __syncthreads();
        {
            uint4* dst = (uint4*)a.Es;
            #pragma unroll
            for (int i = 0; i < 12; ++i) dst[tid + (i << 8)] = pre[i];
        }
        __syncthreads();
        if (l0 + 48 < L_) {
            const uint4* nx = Ebase + ((size_t)(l0 + 48) << 6);
            #pragma unroll
            for (int i = 0; i < 12; ++i) pre[i] = nx[tid + (i << 8)];
        }
        #pragma unroll
        for (int s = 0; s < 12; ++s) {
            const int l = wv * 12 + s;
            const u16* er = &a.Es[(l << 9) + (lane << 3)];
            float acc = 0.f;
            #pragma unroll
            for (int j = 0; j < 8; ++j)
                acc += a.hs[(lane << 3) + j] * b2f(er[j]);
            #pragma unroll
            for (int off = 32; off > 0; off >>= 1)
                acc += __shfl_xor(acc, off);
            if (lane == 0) a.scores[l] = acc;
        }
        __syncthreads();
        float mc = m;
        #pragma unroll
        for (int l = 0; l < 48; ++l) mc = fmaxf(mc, a.scores[l]);
        const float alpha = __expf(m - mc);
        d *= alpha; c0a *= alpha; c1a *= alpha;
        for (int l = 0; l < 48; ++l) {
            const float pl = __expf(a.scores[l] - mc);
            d += pl;
            c0a += pl * b2f(a.Es[(l << 9) + k0]);
            c1a += pl * b2f(a.Es[(l << 9) + k1]);
        }
        m = mc;
    }
    const float inv = 1.0f / d;
    // pack u16 pairs across even/odd lanes -> one agent-scope u32 store each
    const unsigned v0 = f2b(c0a * inv), v1 = f2b(c1a * inv);
    const unsigned n0 = __shfl_xor(v0, 1), n1 = __shfl_xor(v1, 1);
    if (!(tid & 1)) {
        st_ag_u32((unsigned*)&ctxb[((size_t)b << 9) + k0], v0 | (n0 << 16));
        st_ag_u32((unsigned*)&ctxb[((size_t)b << 9) + k1], v1 | (n1 << 16));
    }
}

// Persistent kernel with per-group barriers. blocks 0..127: L0 role (then
// decoder cell); 128..255: L1 role. group g = batch tile g (32 rows).
// attn worker row = g*32 + pos (L0) / g*32 + 16 + pos (L1) — intra-group.
__global__ __launch_bounds__(256, 1) void fused_kernel(
    const u16* __restrict__ xpad,
    const u16* __restrict__ Wih0p, const u16* __restrict__ Whh0b, const float* __restrict__ bias0,
    const u16* __restrict__ Wih1b, const u16* __restrict__ Whh1b, const float* __restrict__ bias1,
    u16* __restrict__ h0a, u16* __restrict__ h0b, float* __restrict__ c0,
    u16* __restrict__ h1a, u16* __restrict__ h1b,
    float* __restrict__ h1f, float* __restrict__ c1,
    u16* __restrict__ E,
    const u16* __restrict__ Wdihb, const u16* __restrict__ Wdhhb,
    const float* __restrict__ biasd, const float* __restrict__ w0col,
    u16* __restrict__ ctxb, float* __restrict__ ypv,
    const float* __restrict__ Wfc, const float* __restrict__ bfc,
    float* __restrict__ out, unsigned* __restrict__ bar)
{
    __shared__ SMU sm;
    const int tid = threadIdx.x;
    const int bid = blockIdx.x;
    const int wv = tid >> 6, lane = tid & 63;
    const int klo = (lane >> 4) << 3;

    const int role = (bid < 128) ? 0 : 1;
    const int id   = role ? (bid - 128) : bid;
    const int g    = id & 7;
    const int pos  = id >> 3;
    const int batch0 = g << 5;
    const int j0     = pos << 5;
    const int myrow  = (g << 5) + (role ? 16 + pos : pos);
    const int me     = (role << 4) | pos;          // 0..31 within group
    unsigned* flags  = bar + (g << 10);            // 4 KB per group
    unsigned ep = 0;

    if (role == 0) {
        {   // ---------------- encoder layer 0 ----------------
            short8 wB[2][18];           // K=64 (x) + K=512 (h) fragments
            #pragma unroll
            for (int nt = 0; nt < 2; ++nt) {
                const size_t row_ = (size_t)((wv << 9) + j0 + (nt << 4) + (lane & 15));
                wB[nt][0] = *(const short8*)(Wih0p + (row_ << 6) + klo);
                wB[nt][1] = *(const short8*)(Wih0p + (row_ << 6) + 32 + klo);
            }
            LOAD_W16_OFS(wB, 2, Whh0b);
            for (int tau = 0; tau <= L_; ++tau) {
                if (tau < L_) {
                    __syncthreads();
                    {   // stage x_t (32 x 64)
                        const int row = tid >> 3, kq = tid & 7;
                        *(uint4*)&sm.enc.in_s[row][kq << 3] =
                            *(const uint4*)(xpad + ((size_t)(batch0 + row) * L_ + tau) * KC + (kq << 3));
                    }
                    uint4 pre2[8];
                    {   // prefetch h0 prev while x-MFMA runs
                        const u16* src1 = (tau & 1) ? h0b : h0a;
                        #pragma unroll
                        for (int i = 0; i < 8; ++i) {
                            const int idx = tid + (i << 8);
                            pre2[i] = *(const uint4*)(src1 + ((size_t)(batch0 + (idx >> 6)) << 9) + ((idx & 63) << 3));
                        }
                    }
                    __syncthreads();
                    f32x4 acc[2][2] = {};
                    MFMA_SEG(2, wB, 0);
                    __syncthreads();
                    #pragma unroll
                    for (int i = 0; i < 8; ++i) {
                        const int idx = tid + (i << 8);
                        *(uint4*)&sm.enc.in_s[idx >> 6][(idx & 63) << 3] = pre2[i];
                    }
                    __syncthreads();
                    MFMA_SEG(16, wB, 2);
                    WRITE_GS();
                    __syncthreads();
                    cell_phase(sm.enc, bias0, nullptr, nullptr, c0,
                               (tau & 1) ? h0a : h0b, nullptr, nullptr, 0,
                               batch0, j0, tid);
                }
                group_barrier(flags, ++ep, me);
            }
        }
        {   // ---------------- decoder: attention + cell ----------------
            short8 wB[2][32];
            LOAD_W16_OFS(wB, 0, Wdihb);
            LOAD_W16_OFS(wB, 16, Wdhhb);
            for (int t = 0; t < PL_; ++t) {
                attn_phase(sm, h1f, E, Wfc, bfc, ctxb, ypv, out, t, myrow, tid);
                group_barrier(flags, ++ep, me);
                step2seg(sm, wB, ctxb, (t & 1) ? h1b : h1a,
                         biasd, w0col, ypv, c1,
                         (t & 1) ? h1a : h1b, h1f, nullptr, 0,
                         batch0, j0, tid, wv, lane, klo);
                group_barrier(flags, ++ep, me);
            }
        }
        attn_phase(sm, h1f, E, Wfc, bfc, ctxb, ypv, out, PL_, myrow, tid);
    } else {
        {   // ---------------- encoder layer 1 (one step behind) ----------------
            short8 wB[2][32];
            LOAD_W16_OFS(wB, 0, Wih1b);
            LOAD_W16_OFS(wB, 16, Whh1b);
            for (int tau = 0; tau <= L_; ++tau) {
                if (tau >= 1) {
                    const int te = tau - 1;
                    step2seg(sm, wB,
                             (tau & 1) ? h0b : h0a,            // ys0[te]
                             (te & 1) ? h1b : h1a,             // h1 prev
                             bias1, nullptr, nullptr, c1,
                             (te & 1) ? h1a : h1b, h1f, E, te,
                             batch0, j0, tid, wv, lane, klo);
                }
                group_barrier(flags, ++ep, me);
            }
        }
        for (int t = 0; t < PL_; ++t) {
            attn_phase(sm, h1f, E, Wfc, bfc, ctxb, ypv, out, t, myrow, tid);
            group_barrier(flags, ++ep, me);
            group_barrier(flags, ++ep, me);   // cell phase runs on L0-role blocks
        }
        attn_phase(sm, h1f, E, Wfc, bfc, ctxb, ypv, out, PL_, myrow, tid);
    }
}

// ===================== verified multi-launch fallback path =====================

struct Seg { const u16* src; int stride; const u16* W; int nch; int ldw; };

struct SMOld {
    u16   in_s[BT][KC + 8];
    u16   w_s[GT][KC + 8];
    float g_s[GT][BT + 1];
};

__device__ void gates_gemm_cell(const Seg* segs,
    const float* __restrict__ bias, const float* __restrict__ w0col,
    const float* __restrict__ yprev,
    float* __restrict__ cbuf, u16* __restrict__ hbf_out, float* __restrict__ hf_out,
    u16* __restrict__ Ebuf, int te, int batch0, int j0, SMOld& sm)
{
    const int tid = threadIdx.x;
    const int wv = tid >> 6, lane = tid & 63;
    f32x4 acc[2][2] = {};

    for (int s = 0; s < 2; ++s) {
        const Seg sg = segs[s];
        for (int c = 0; c < sg.nch; ++c) {
            const int k0 = c * KC;
            __syncthreads();
            {
                const int b = tid >> 3, kq = tid & 7;
                const uint4* p = (const uint4*)(sg.src + (size_t)(batch0 + b) * sg.stride + k0) + kq;
                *(uint4*)&sm.in_s[b][kq << 3] = *p;
            }
            #pragma unroll
            for (int i = 0; i < 4; ++i) {
                const int idx = tid + (i << 8);
                const int gi = idx >> 3, kq = idx & 7;
                const int row = ((gi >> 5) << 9) + j0 + (gi & 31);
                const uint4* p = (const uint4*)(sg.W + (size_t)row * sg.ldw + k0) + kq;
                *(uint4*)&sm.w_s[gi][kq << 3] = *p;
            }
            __syncthreads();
            #pragma unroll
            for (int ks = 0; ks < 2; ++ks) {
                const int kk = (ks << 5) + ((lane >> 4) << 3);
                short8 a0 = *(const short8*)&sm.in_s[lane & 15][kk];
                short8 a1 = *(const short8*)&sm.in_s[16 + (lane & 15)][kk];
                #pragma unroll
                for (int nt = 0; nt < 2; ++nt) {
                    const int gi = (((wv << 1) + nt) << 4) + (lane & 15);
                    short8 bb = *(const short8*)&sm.w_s[gi][kk];
                    acc[0][nt] = __builtin_amdgcn_mfma_f32_16x16x32_bf16(a0, bb, acc[0][nt], 0, 0, 0);
                    acc[1][nt] = __builtin_amdgcn_mfma_f32_16x16x32_bf16(a1, bb, acc[1][nt], 0, 0, 0);
                }
            }
        }
    }
    __syncthreads();
    #pragma unroll
    for (int mt = 0; mt < 2; ++mt)
        #pragma unroll
        for (int nt = 0; nt < 2; ++nt) {
            const int gi = (((wv << 1) + nt) << 4) + (lane & 15);
            const int brow = (mt << 4) + ((lane >> 4) << 2);
            #pragma unroll
            for (int r = 0; r < 4; ++r)
                sm.g_s[gi][brow + r] = acc[mt][nt][r];
        }
    __syncthreads();

    #pragma unroll
    for (int e = 0; e < 4; ++e) {
        const int idx = tid + (e << 8);
        const int b = idx >> 5, j = idx & 31;
        const int bg = batch0 + b, jg = j0 + j;
        float pre[4];
        #pragma unroll
        for (int q = 0; q < 4; ++q) {
            const int r = (q << 9) + jg;
            float v = sm.g_s[(q << 5) + j][b] + bias[r];
            if (w0col) v += yprev[bg] * w0col[r];
            pre[q] = v;
        }
        const float iv = sigm(pre[0]);
        const float fv = sigm(pre[1]);
        const float gv = tanhf_(pre[2]);
        const float ov = sigm(pre[3]);
        const size_t ci = ((size_t)bg << 9) + jg;
        const float cold = cbuf[ci];
        const float cn = fv * cold + iv * gv;
        const float hn = ov * tanhf_(cn);
        cbuf[ci] = cn;
        hbf_out[ci] = f2b(hn);
        if (hf_out) hf_out[ci] = hn;
        if (Ebuf) Ebuf[((size_t)bg * L_ + te) * H_ + jg] = f2b(hn);
    }
}

__global__ __launch_bounds__(256) void enc_step_kernel(
    const u16* __restrict__ xpad, const u16* __restrict__ Wih0p, const u16* __restrict__ Whh0b,
    const float* __restrict__ bias0,
    const u16* __restrict__ Wih1b, const u16* __restrict__ Whh1b, const float* __restrict__ bias1,
    u16* h0a, u16* h0b, float* c0,
    u16* h1a, u16* h1b, float* h1fa, float* h1fb, float* c1,
    u16* E, int tau)
{
    __shared__ SMOld sm;
    const int bid = blockIdx.x;
    if (bid < 128) {
        if (tau >= L_) return;
        const int tb = bid & 7, th = bid >> 3;
        Seg segs[2];
        segs[0] = { xpad + tau * KC, L_ * KC, Wih0p, 1, KC };
        segs[1] = { (tau & 1) ? h0b : h0a, H_, Whh0b, 8, H_ };
        gates_gemm_cell(segs, bias0, nullptr, nullptr, c0,
                        (tau & 1) ? h0a : h0b, nullptr, nullptr, 0,
                        tb * BT, th * 32, sm);
    } else {
        if (tau == 0) return;
        const int te = tau - 1;
        const int id = bid - 128;
        const int tb = id & 7, th = id >> 3;
        Seg segs[2];
        segs[0] = { (tau & 1) ? h0b : h0a, H_, Wih1b, 8, H_ };
        segs[1] = { (te & 1) ? h1b : h1a, H_, Whh1b, 8, H_ };
        gates_gemm_cell(segs, bias1, nullptr, nullptr, c1,
                        (te & 1) ? h1a : h1b, (te & 1) ? h1fa : h1fb, E, te,
                        tb * BT, th * 32, sm);
    }
}

__global__ __launch_bounds__(256) void dec_step_kernel(
    const u16* __restrict__ ctxb, const float* __restrict__ yprev,
    const u16* __restrict__ Wdihb, const u16* __restrict__ Wdhhb,
    const float* __restrict__ biasd, const float* __restrict__ w0col,
    u16* h1a, u16* h1b, float* h1fa, float* h1fb, float* c1, int t)
{
    __shared__ SMOld sm;
    const int bid = blockIdx.x;
    const int tb = bid & 7, th = bid >> 3;
    Seg segs[2];
    segs[0] = { ctxb, H_, Wdihb, 8, H_ };
    segs[1] = { (t & 1) ? h1b : h1a, H_, Wdhhb, 8, H_ };
    gates_gemm_cell(segs, biasd, w0col, yprev, c1,
                    (t & 1) ? h1a : h1b, (t & 1) ? h1fa : h1fb, nullptr, 0,
                    tb * BT, th * 32, sm);
}

__global__ __launch_bounds__(256) void attn_step_kernel(
    const float* __restrict__ hf, const u16* __restrict__ E,
    const float* __restrict__ Wfc, const float* __restrict__ bfc,
    u16* __restrict__ ctxb, float* __restrict__ yprev,
    float* __restrict__ out, int step)
{
    __shared__ float hs[H_];
    __shared__ float red[256];
    __shared__ u16 Es[48 * H_];
    __shared__ float scores[48];
    const int tid = threadIdx.x;
    const int b = blockIdx.x;

    hs[tid]       = hf[((size_t)b << 9) + tid];
    hs[tid + 256] = hf[((size_t)b << 9) + tid + 256];
    __syncthreads();

    float p = hs[tid] * Wfc[tid] + hs[tid + 256] * Wfc[tid + 256];
    red[tid] = p;
    __syncthreads();
    for (int s = 128; s > 0; s >>= 1) {
        if (tid < s) red[tid] += red[tid + s];
        __syncthreads();
    }
    if (tid == 0) {
        if (step > 0) {
            float y = red[0] + bfc[0];
            yprev[b] = y;
            out[b * PL_ + (step - 1)] = y;
        } else {
            yprev[b] = 0.0f;
        }
    }
    if (step == PL_) return;

    const int wv = tid >> 6, lane = tid & 63;
    float m = -1e30f, d = 0.0f, c0a = 0.0f, c1a = 0.0f;
    const int k0 = tid, k1 = tid + 256;

    for (int l0 = 0; l0 < L_; l0 += 48) {
        __syncthreads();
        {
            const uint4* src = (const uint4*)(E + (((size_t)b * L_ + l0) << 9));
            uint4* dst = (uint4*)Es;
            #pragma unroll
            for (int i = 0; i < 12; ++i)
                dst[tid + (i << 8)] = src[tid + (i << 8)];
        }
        __syncthreads();
        #pragma unroll
        for (int s = 0; s < 12; ++s) {
            const int l = wv * 12 + s;
            const u16* er = &Es[(l << 9) + (lane << 3)];
            float acc = 0.f;
            #pragma unroll
            for (int j = 0; j < 8; ++j)
                acc += hs[(lane << 3) + j] * b2f(er[j]);
            #pragma unroll
            for (int off = 32; off > 0; off >>= 1)
                acc += __shfl_xor(acc, off);
            if (lane == 0) scores[l] = acc;
        }
        __syncthreads();
        float mc = m;
        #pragma unroll
        for (int l = 0; l < 48; ++l) mc = fmaxf(mc, scores[l]);
        const float alpha = __expf(m - mc);
        d *= alpha; c0a *= alpha; c1a *= alpha;
        for (int l = 0; l < 48; ++l) {
            const float pl = __expf(scores[l] - mc);
            d += pl;
            c0a += pl * b2f(Es[(l << 9) + k0]);
            c1a += pl * b2f(Es[(l << 9) + k1]);
        }
        m = mc;
    }
    const float inv = 1.0f / d;
    ctxb[((size_t)b << 9) + k0] = f2b(c0a * inv);
    ctxb[((size_t)b << 9) + k1] = f2b(c1a * inv);
}

// One-time (per call) weight conversion fp32->bf16, bias fusion, x padding to K=64.
__global__ __launch_bounds__(256) void prep_kernel(
    const float* __restrict__ x,
    const float* __restrict__ Wih0, const float* __restrict__ Whh0,
    const float* __restrict__ bih0, const float* __restrict__ bhh0,
    const float* __restrict__ Wih1, const float* __restrict__ Whh1,
    const float* __restrict__ bih1, const float* __restrict__ bhh1,
    const float* __restrict__ Wdih, const float* __restrict__ Wdhh,
    const float* __restrict__ bihd, const float* __restrict__ bhhd,
    u16* Wih0p, u16* Whh0b, u16* Wih1b, u16* Whh1b, u16* Wdihb, u16* Wdhhb,
    float* w0col, float* bias0, float* bias1, float* biasd, u16* xpad)
{
    const long E0 = 131072;
    const long E1 = E0 + 1048576;
    const long E2 = E1 + 1048576;
    const long E3 = E2 + 1048576;
    const long E4 = E3 + 1048576;
    const long E5 = E4 + 1048576;
    const long E6 = E5 + 2048;
    const long E7 = E6 + 2048;
    const long E8 = E7 + 2048;
    const long E9 = E8 + 2048;
    const long E10 = E9 + (long)B_ * L_ * KC;
    for (long idx = (long)blockIdx.x * 256 + threadIdx.x; idx < E10;
         idx += (long)gridDim.x * 256) {
        if (idx < E0) {
            long r = idx >> 6, cc = idx & 63;
            Wih0p[idx] = f2b(cc < NIN ? Wih0[(r << 3) + cc] : 0.0f);
        } else if (idx < E1) { long j = idx - E0; Whh0b[j] = f2b(Whh0[j]);
        } else if (idx < E2) { long j = idx - E1; Wih1b[j] = f2b(Wih1[j]);
        } else if (idx < E3) { long j = idx - E2; Whh1b[j] = f2b(Whh1[j]);
        } else if (idx < E4) {
            long j = idx - E3; long r = j >> 9, cc = j & 511;
            Wdihb[j] = f2b(Wdih[r * 513 + 1 + cc]);
        } else if (idx < E5) { long j = idx - E4; Wdhhb[j] = f2b(Wdhh[j]);
        } else if (idx < E6) { long j = idx - E5; w0col[j] = Wdih[j * 513];
        } else if (idx < E7) { long j = idx - E6; bias0[j] = bih0[j] + bhh0[j];
        } else if (idx < E8) { long j = idx - E7; bias1[j] = bih1[j] + bhh1[j];
        } else if (idx < E9) { long j = idx - E8; biasd[j] = bihd[j] + bhhd[j];
        } else {
            long j = idx - E9;
            long b = j / (L_ * KC);
            long rest = j - b * (L_ * KC);
            long l = rest >> 6, n = rest & 63;
            xpad[j] = f2b(n < NIN ? x[(b * L_ + l) * NIN + n] : 0.0f);
        }
    }
}

extern "C" void kernel_launch(void* const* d_in, const int* in_sizes, int n_in,
                              void* d_out, int out_size, void* d_ws, size_t ws_size,
                              hipStream_t stream)
{
    (void)in_sizes; (void)n_in; (void)out_size; (void)ws_size;
    const float* x    = (const float*)d_in[0];
    const float* Wih0 = (const float*)d_in[1];
    const float* Whh0 = (const float*)d_in[2];
    const float* bih0 = (const float*)d_in[3];
    const float* bhh0 = (const float*)d_in[4];
    const float* Wih1 = (const float*)d_in[5];
    const float* Whh1 = (const float*)d_in[6];
    const float* bih1 = (const float*)d_in[7];
    const float* bhh1 = (const float*)d_in[8];
    const float* Wdih = (const float*)d_in[9];
    const float* Wdhh = (const float*)d_in[10];
    const float* bihd = (const float*)d_in[11];
    const float* bhhd = (const float*)d_in[12];
    const float* Wfc  = (const float*)d_in[13];
    const float* bfc  = (const float*)d_in[14];
    float* out = (float*)d_out;

    char* ws = (char*)d_ws;
    float* c0    = (float*)(ws + 0);
    float* c1    = (float*)(ws + 524288);
    u16*   h0a   = (u16*)(ws + 1048576);
    u16*   h1a   = (u16*)(ws + 1310720);
    // zero region ends at 1572864
    u16*   h0b   = (u16*)(ws + 1572864);
    u16*   h1b   = (u16*)(ws + 1835008);
    float* h1fa  = (float*)(ws + 2097152);      // fused path: the single h1f
    unsigned* bar = (unsigned*)(ws + 2621440);  // 32 KB barrier flags (old h1fb slot)
    float* h1fb  = (float*)(ws + 2621440);      // fallback path only
    u16*   ctxb  = (u16*)(ws + 3145728);
    float* ypv   = (float*)(ws + 3407872);
    u16*   Wih0p = (u16*)(ws + 3408896);
    u16*   Whh0b = (u16*)(ws + 3671040);
    u16*   Wih1b = (u16*)(ws + 5768192);
    u16*   Whh1b = (u16*)(ws + 7865344);
    u16*   Wdihb = (u16*)(ws + 9962496);
    u16*   Wdhhb = (u16*)(ws + 12059648);
    float* w0col = (float*)(ws + 14156800);
    float* bias0 = (float*)(ws + 14164992);
    float* bias1 = (float*)(ws + 14173184);
    float* biasd = (float*)(ws + 14181376);
    u16*   xpad  = (u16*)(ws + 14189568);
    u16*   E     = (u16*)(ws + 25199616);
    // total workspace use: 113,280,000 bytes (unchanged)

    hipMemsetAsync(d_ws, 0, 1572864, stream);        // c0, c1, h0[0], h1[0] = 0
    hipMemsetAsync(ws + 2621440, 0, 32768, stream);  // barrier flags = 0

    prep_kernel<<<512, 256, 0, stream>>>(x, Wih0, Whh0, bih0, bhh0,
        Wih1, Whh1, bih1, bhh1, Wdih, Wdhh, bihd, bhhd,
        Wih0p, Whh0b, Wih1b, Whh1b, Wdihb, Wdhhb, w0col, bias0, bias1, biasd, xpad);

    void* kargs[] = {
        (void*)&xpad,
        (void*)&Wih0p, (void*)&Whh0b, (void*)&bias0,
        (void*)&Wih1b, (void*)&Whh1b, (void*)&bias1,
        (void*)&h0a, (void*)&h0b, (void*)&c0,
        (void*)&h1a, (void*)&h1b, (void*)&h1fa, (void*)&c1,
        (void*)&E,
        (void*)&Wdihb, (void*)&Wdhhb, (void*)&biasd, (void*)&w0col,
        (void*)&ctxb, (void*)&ypv,
        (void*)&Wfc, (void*)&bfc,
        (void*)&out, (void*)&bar
    };
    hipError_t rc = hipLaunchCooperativeKernel(fused_kernel, dim3(256), dim3(256),
                                               kargs, 0, stream);
    if (rc != hipSuccess) {
        // co-residency validation failed -> verified multi-launch path
        (void)hipGetLastError();   // clear sticky error
        for (int tau = 0; tau <= L_; ++tau)
            enc_step_kernel<<<256, 256, 0, stream>>>(xpad, Wih0p, Whh0b, bias0,
                Wih1b, Whh1b, bias1, h0a, h0b, c0, h1a, h1b, h1fa, h1fb, c1, E, tau);
        for (int t = 0; t < PL_; ++t) {
            attn_step_kernel<<<256, 256, 0, stream>>>((t & 1) ? h1fb : h1fa, E,
                Wfc, bfc, ctxb, ypv, out, t);
            dec_step_kernel<<<128, 256, 0, stream>>>(ctxb, ypv, Wdihb, Wdhhb,
                biasd, w0col, h1a, h1b, h1fa, h1fb, c1, t);
        }
        attn_step_kernel<<<256, 256, 0, stream>>>(h1fa, E, Wfc, bfc, ctxb, ypv, out, PL_);
    }
}